// Round 1
// baseline (654.176 us; speedup 1.0000x reference)
//
#include <hip/hip_runtime.h>
#include <hip/hip_bf16.h>
#include <math.h>

// ---------------- problem constants ----------------
#define BN   1
#define DIMC 192
#define HI   48
#define WI   48
#define LL   2304          // HI*WI
#define EE   384
#define NN   16
#define PP   64
#define HHH  6
#define HALF 8
#define KK   4
#define BK_SEQ (BN*KK)     // 4
#define NBH  (BK_SEQ*HHH)  // 24
#define CLEN 96
#define NCHUNK 24          // CLEN*NCHUNK == LL
#define ZLD  816           // padded leading dim for zx|bc|dt (806 logical)
#define ZN   806

static __device__ __forceinline__ float siluf(float v) {
    return v / (1.f + expf(-v));
}

// ---------------- K0: build x_seq (4,2304,192) ----------------
__global__ __launch_bounds__(256) void k_build_xseq(const float* __restrict__ x,
                                                    float* __restrict__ xseq) {
    int idx = blockIdx.x * 256 + threadIdx.x;
    if (idx >= KK * LL * DIMC) return;
    int d = idx % DIMC;
    int l = (idx / DIMC) % LL;
    int k = idx / (DIMC * LL);
    int dim = l / 12;
    int pos = (l % 12) * DIMC + d;   // in [0,2304)
    int src;
    if (k == 0)      src = pos;
    else if (k == 1) src = (pos % 48) * 48 + pos / 48;
    else if (k == 2) src = 2303 - pos;
    else { int p2 = 2303 - pos; src = (p2 % 48) * 48 + p2 / 48; }
    xseq[idx] = x[dim * LL + src];
}

// ---------------- Kprep: concat weights w_zx|w_bc|w_dt and bias ----------------
__global__ __launch_bounds__(256) void k_prep_w(const float* __restrict__ w_zx,
                                                const float* __restrict__ w_bc,
                                                const float* __restrict__ b_bc,
                                                const float* __restrict__ w_dt,
                                                const float* __restrict__ dt_bias,
                                                float* __restrict__ wcat,
                                                float* __restrict__ bcat) {
    int idx = blockIdx.x * 256 + threadIdx.x;
    if (idx < EE * ZLD) {
        int k = idx / ZLD, j = idx % ZLD;
        float v = 0.f;
        if (j < 768)      v = w_zx[k * 768 + j];
        else if (j < 800) v = w_bc[k * 32 + (j - 768)];
        else if (j < ZN)  v = w_dt[k * 6 + (j - 800)];
        wcat[idx] = v;
    }
    if (idx < ZLD) {
        float bv = 0.f;
        if (idx >= 768 && idx < 800) bv = b_bc[idx - 768];
        else if (idx >= 800 && idx < ZN) bv = dt_bias[idx - 800];
        bcat[idx] = bv;
    }
}

// ---------------- generic fp32 GEMM: C = A(MxK) * B(KxN) (+bias) ----------------
// M % 128 == 0, K % 16 == 0 assumed. N guarded.
__global__ __launch_bounds__(256) void gemm_f32(const float* __restrict__ A,
                                                const float* __restrict__ B,
                                                const float* __restrict__ bias,
                                                float* __restrict__ C,
                                                int M, int N, int K, int ldb, int ldc) {
    const int BM = 128, BNt = 128, BKt = 16;
    __shared__ float As[BKt][BM + 4];
    __shared__ float Bs[BKt][BNt + 4];
    int bm = blockIdx.y * BM, bn = blockIdx.x * BNt;
    int tid = threadIdx.x;
    int tx = tid & 15, ty = tid >> 4;
    float acc[8][8];
#pragma unroll
    for (int i = 0; i < 8; i++)
#pragma unroll
        for (int j = 0; j < 8; j++) acc[i][j] = 0.f;

    for (int k0 = 0; k0 < K; k0 += BKt) {
        {
            int m = tid >> 1;
            int ks = (tid & 1) * 8;
            const float* ap = A + (size_t)(bm + m) * K + k0 + ks;
#pragma unroll
            for (int j = 0; j < 8; j++) As[ks + j][m] = ap[j];
        }
        {
            int kk = tid >> 4;
            int ns = (tid & 15) * 8;
            const float* bp = B + (size_t)(k0 + kk) * ldb + bn + ns;
#pragma unroll
            for (int j = 0; j < 8; j++)
                Bs[kk][ns + j] = (bn + ns + j < N) ? bp[j] : 0.f;
        }
        __syncthreads();
#pragma unroll
        for (int kk = 0; kk < BKt; kk++) {
            float a[8], b[8];
#pragma unroll
            for (int i = 0; i < 8; i++) a[i] = As[kk][ty * 8 + i];
#pragma unroll
            for (int j = 0; j < 8; j++) b[j] = Bs[kk][tx * 8 + j];
#pragma unroll
            for (int i = 0; i < 8; i++)
#pragma unroll
                for (int j = 0; j < 8; j++) acc[i][j] += a[i] * b[j];
        }
        __syncthreads();
    }
#pragma unroll
    for (int i = 0; i < 8; i++) {
        int m = bm + ty * 8 + i;
#pragma unroll
        for (int j = 0; j < 8; j++) {
            int n = bn + tx * 8 + j;
            if (n < N) {
                float v = acc[i][j];
                if (bias) v += bias[n];
                C[(size_t)m * ldc + n] = v;
            }
        }
    }
}

// ---------------- K2: xact = silu(proj[:, 0:384]) ----------------
__global__ __launch_bounds__(256) void k_act(const float* __restrict__ proj,
                                             float* __restrict__ xact) {
    int idx = blockIdx.x * 256 + threadIdx.x;
    if (idx >= KK * LL * EE) return;
    int row = idx / EE, e = idx % EE;
    float v = proj[(size_t)row * 768 + e];
    xact[idx] = siluf(v);
}

// ---------------- K3: dt/r/dh in (bh, l) layout ----------------
__global__ __launch_bounds__(256) void k_dtr(const float* __restrict__ zxb,
                                             const float* __restrict__ A_log,
                                             float* __restrict__ dtv,
                                             float* __restrict__ rrv,
                                             float* __restrict__ dhv) {
    int idx = blockIdx.x * 256 + threadIdx.x;
    if (idx >= NBH * LL) return;
    int bh = idx / LL, l = idx % LL;
    int b = bh / HHH, h = bh % HHH;
    float xv = zxb[((size_t)b * LL + l) * ZLD + 800 + h];
    float sp = fmaxf(xv, 0.f) + log1pf(expf(-fabsf(xv)));   // softplus
    float r = expf(-sp * expf(A_log[h]));
    dtv[idx] = sp;
    rrv[idx] = r;
    dhv[idx] = 0.5f * sp;
}

// ---------------- K4: cumsum of dt over l, per (bh) ----------------
__global__ __launch_bounds__(256) void k_cumsum(const float* __restrict__ dtv,
                                                float* __restrict__ cum) {
    int bh = blockIdx.x;
    int tid = threadIdx.x;
    const float* src = dtv + (size_t)bh * LL;
    float* dst = cum + (size_t)bh * LL;
    const int PER = 9;                    // 256*9 = 2304
    int base = tid * PER;
    float v[PER], p[PER];
    float s = 0.f;
#pragma unroll
    for (int j = 0; j < PER; j++) { v[j] = src[base + j]; s += v[j]; p[j] = s; }
    __shared__ float sh[256];
    sh[tid] = s;
    __syncthreads();
    for (int off = 1; off < 256; off <<= 1) {
        float t = (tid >= off) ? sh[tid - off] : 0.f;
        __syncthreads();
        sh[tid] += t;
        __syncthreads();
    }
    float excl = sh[tid] - s;
#pragma unroll
    for (int j = 0; j < PER; j++) dst[base + j] = excl + p[j];
}

// ---------------- K5: RMS-normalize B/C and rotate -> btct (bh, l, 32) ----------------
__global__ __launch_bounds__(256) void k_rot(const float* __restrict__ zxb,
                                             const float* __restrict__ cum,
                                             const float* __restrict__ theta,
                                             float* __restrict__ btct) {
    int idx = blockIdx.x * 256 + threadIdx.x;
    if (idx >= BK_SEQ * LL) return;
    int b = idx / LL, l = idx % LL;
    const float* bcrow = zxb + ((size_t)b * LL + l) * ZLD + 768;
    float Bm[16], Cm[16];
    float sb = 0.f, sc = 0.f;
#pragma unroll
    for (int j = 0; j < 16; j++) {
        Bm[j] = bcrow[j];      sb += Bm[j] * Bm[j];
        Cm[j] = bcrow[16 + j]; sc += Cm[j] * Cm[j];
    }
    float rb = rsqrtf(sb * (1.f / 16.f) + 1e-6f);
    float rc = rsqrtf(sc * (1.f / 16.f) + 1e-6f);
#pragma unroll
    for (int h = 0; h < HHH; h++) {
        float cd = cum[((size_t)b * HHH + h) * LL + l];
        float* out = btct + (((size_t)b * HHH + h) * LL + l) * 32;
#pragma unroll
        for (int j = 0; j < 8; j++) {
            float ang = cd * theta[h * 8 + j];
            float cc = cosf(ang), ss = sinf(ang);
            float b0 = Bm[2 * j] * rb, b1 = Bm[2 * j + 1] * rb;
            out[2 * j]     = b0 * cc + b1 * ss;
            out[2 * j + 1] = -b0 * ss + b1 * cc;
            float c0 = Cm[2 * j] * rc, c1 = Cm[2 * j + 1] * rc;
            out[16 + 2 * j]     = c0 * cc + c1 * ss;
            out[16 + 2 * j + 1] = -c0 * ss + c1 * cc;
        }
    }
}

// ---------------- K6: pack xh into (bh, l, 64) ----------------
__global__ __launch_bounds__(256) void k_pack_xh(const float* __restrict__ zxb,
                                                 float* __restrict__ xh) {
    int idx = blockIdx.x * 256 + threadIdx.x;
    if (idx >= NBH * LL * PP) return;
    int p = idx % PP;
    int l = (idx / PP) % LL;
    int bh = idx / (PP * LL);
    int b = bh / HHH, h = bh % HHH;
    xh[idx] = zxb[((size_t)b * LL + l) * ZLD + EE + h * PP + p];
}

// ---------------- scan phases A (mode 0) and C (mode 1) ----------------
__global__ __launch_bounds__(64) void k_scan_phase(const float* __restrict__ btct,
                                                   const float* __restrict__ rrv,
                                                   const float* __restrict__ dhv,
                                                   const float* __restrict__ xh,
                                                   const float* __restrict__ h0,
                                                   float* __restrict__ Hc,
                                                   float* __restrict__ Rc,
                                                   float* __restrict__ yD,
                                                   const float* __restrict__ Dsk,
                                                   int mode) {
    int chunk = blockIdx.x;   // 0..23
    int bh = blockIdx.y;      // 0..23
    int lane = threadIdx.x;   // p
    int b = bh / HHH, h = bh % HHH;
    int t0 = chunk * CLEN;
    const float* bt_row = btct + (size_t)bh * LL * 32;
    const float* rr_row = rrv + (size_t)bh * LL;
    const float* dh_row = dhv + (size_t)bh * LL;
    const float* xh_row = xh + (size_t)bh * LL * PP;

    float hreg[16];
    if (mode == 0) {
#pragma unroll
        for (int n = 0; n < 16; n++) hreg[n] = 0.f;
    } else {
        const float* hp = h0 + ((size_t)(chunk * NBH + bh) * 16) * PP + lane;
#pragma unroll
        for (int n = 0; n < 16; n++) hreg[n] = hp[n * PP];
    }
    float Btp[16];
    float xprev = 0.f;
    if (t0 > 0) {
        xprev = xh_row[(size_t)(t0 - 1) * PP + lane];
#pragma unroll
        for (int n = 0; n < 16; n++) Btp[n] = bt_row[(size_t)(t0 - 1) * 32 + n];
    } else {
#pragma unroll
        for (int n = 0; n < 16; n++) Btp[n] = 0.f;
    }
    float Rprod = 1.f;
    float dsk = Dsk[h];

    for (int t = t0; t < t0 + CLEN; ++t) {
        float r = rr_row[t];
        float dhalf = dh_row[t];
        float xcur = xh_row[(size_t)t * PP + lane];
        const float* bb = bt_row + (size_t)t * 32;
        float a = dhalf * xcur;
        float ap = dhalf * r * xprev;
        float y = 0.f;
#pragma unroll
        for (int n = 0; n < 16; n++) {
            float Btn = bb[n];
            hreg[n] = r * hreg[n] + a * Btn + ap * Btp[n];
            Btp[n] = Btn;
            if (mode) y += bb[16 + n] * hreg[n];
        }
        xprev = xcur;
        if (mode) {
            yD[((size_t)b * LL + t) * EE + h * PP + lane] = y + dsk * xcur;
        } else {
            Rprod *= r;
        }
    }
    if (mode == 0) {
        float* Hp = Hc + ((size_t)(chunk * NBH + bh) * 16) * PP + lane;
#pragma unroll
        for (int n = 0; n < 16; n++) Hp[n * PP] = hreg[n];
        if (lane == 0) Rc[chunk * NBH + bh] = Rprod;
    }
}

// ---------------- scan phase B: combine chunk summaries ----------------
__global__ __launch_bounds__(64) void k_scan_combine(const float* __restrict__ Hc,
                                                     const float* __restrict__ Rc,
                                                     float* __restrict__ h0) {
    int bh = blockIdx.x;
    int lane = threadIdx.x;
    float s[16];
#pragma unroll
    for (int n = 0; n < 16; n++) s[n] = 0.f;
    float* out0 = h0 + ((size_t)(0 * NBH + bh) * 16) * PP + lane;
#pragma unroll
    for (int n = 0; n < 16; n++) out0[n * PP] = 0.f;
    for (int c = 0; c < NCHUNK - 1; ++c) {
        float R = Rc[c * NBH + bh];
        const float* Hp = Hc + ((size_t)(c * NBH + bh) * 16) * PP + lane;
        float* op = h0 + ((size_t)((c + 1) * NBH + bh) * 16) * PP + lane;
#pragma unroll
        for (int n = 0; n < 16; n++) {
            s[n] = R * s[n] + Hp[n * PP];
            op[n * PP] = s[n];
        }
    }
}

// ---------------- K8: g = rms(y * silu(z)) * rms_w ----------------
__global__ __launch_bounds__(128) void k_gmul(const float* __restrict__ yD,
                                              const float* __restrict__ zxb,
                                              const float* __restrict__ rms_w,
                                              float* __restrict__ g) {
    int row = blockIdx.x;
    int tid = threadIdx.x;
    int lane = tid & 63, wid = tid >> 6;
    float v[3];
    float ss = 0.f;
#pragma unroll
    for (int j = 0; j < 3; j++) {
        int e = tid * 3 + j;
        float y = yD[(size_t)row * EE + e];
        float z = zxb[(size_t)row * ZLD + e];
        v[j] = y * siluf(z);
        ss += v[j] * v[j];
    }
#pragma unroll
    for (int off = 1; off < 64; off <<= 1) ss += __shfl_xor(ss, off);
    __shared__ float red[2];
    if (lane == 0) red[wid] = ss;
    __syncthreads();
    float total = red[0] + red[1];
    float scale = rsqrtf(total * (1.f / (float)EE) + 1e-6f);
#pragma unroll
    for (int j = 0; j < 3; j++) {
        int e = tid * 3 + j;
        g[(size_t)row * EE + e] = v[j] * scale * rms_w[e];
    }
}

// ---------------- K9: gate + 4-direction merge -> mergedT (l, e) ----------------
__global__ __launch_bounds__(256) void k_merge(const float* __restrict__ mres,
                                               const float* __restrict__ proj,
                                               float* __restrict__ mrg) {
    int idx = blockIdx.x * 256 + threadIdx.x;
    if (idx >= LL * EE) return;
    int e = idx % EE, l = idx / EE;
    int l1 = (l % 48) * 48 + l / 48;
    int rows[4];
    rows[0] = 0 * LL + l;
    rows[1] = 1 * LL + l1;
    rows[2] = 2 * LL + (2303 - l);
    rows[3] = 3 * LL + (2303 - l1);
    float acc = 0.f;
#pragma unroll
    for (int k = 0; k < 4; k++) {
        float m = mres[(size_t)rows[k] * EE + e];
        float gz = proj[(size_t)rows[k] * 768 + EE + e];
        acc += m * siluf(gz);
    }
    mrg[idx] = acc;
}

// ---------------- K10: LayerNorm over channels + residual ----------------
__global__ __launch_bounds__(64) void k_ln(const float* __restrict__ outT,
                                           const float* __restrict__ x,
                                           const float* __restrict__ ln_g,
                                           const float* __restrict__ ln_b,
                                           const float* __restrict__ res_scale,
                                           float* __restrict__ outF) {
    int l = blockIdx.x;
    int lane = threadIdx.x;
    float v[3];
    float s = 0.f;
#pragma unroll
    for (int j = 0; j < 3; j++) {
        int d = lane * 3 + j;
        v[j] = outT[(size_t)l * DIMC + d];
        s += v[j];
    }
#pragma unroll
    for (int off = 1; off < 64; off <<= 1) s += __shfl_xor(s, off);
    float mu = s * (1.f / (float)DIMC);
    float sq = 0.f;
#pragma unroll
    for (int j = 0; j < 3; j++) { float dlt = v[j] - mu; sq += dlt * dlt; }
#pragma unroll
    for (int off = 1; off < 64; off <<= 1) sq += __shfl_xor(sq, off);
    float rstd = rsqrtf(sq * (1.f / (float)DIMC) + 1e-5f);
    float rs = res_scale[0];
#pragma unroll
    for (int j = 0; j < 3; j++) {
        int d = lane * 3 + j;
        outF[(size_t)d * LL + l] =
            x[(size_t)d * LL + l] + rs * ((v[j] - mu) * rstd * ln_g[d] + ln_b[d]);
    }
}

// ---------------- host launcher ----------------
extern "C" void kernel_launch(void* const* d_in, const int* in_sizes, int n_in,
                              void* d_out, int out_size, void* d_ws, size_t ws_size,
                              hipStream_t stream) {
    const float* x        = (const float*)d_in[0];
    const float* w_in     = (const float*)d_in[1];
    const float* w_zx     = (const float*)d_in[2];
    const float* w_bc     = (const float*)d_in[3];
    const float* b_bc     = (const float*)d_in[4];
    const float* w_dt     = (const float*)d_in[5];
    const float* dt_bias  = (const float*)d_in[6];
    const float* A_log    = (const float*)d_in[7];
    const float* theta    = (const float*)d_in[8];
    const float* D_skip   = (const float*)d_in[9];
    const float* rms_w    = (const float*)d_in[10];
    const float* w_mout   = (const float*)d_in[11];
    const float* w_out    = (const float*)d_in[12];
    const float* ln_g     = (const float*)d_in[13];
    const float* ln_b     = (const float*)d_in[14];
    const float* res_scale= (const float*)d_in[15];
    float* outF = (float*)d_out;
    float* ws = (float*)d_ws;

    // workspace layout (floats), with aliasing
    size_t o = 0;
    auto alloc = [&](size_t n) { size_t r = o; o += (n + 127) & ~(size_t)127; return r; };
    size_t xseq_o = alloc(1769472);              // reused as btct after G1
    size_t proj_o = alloc((size_t)9216 * 768);
    size_t xact_o = alloc((size_t)9216 * 384);   // reused as xh after G2
    size_t wcat_o = alloc((size_t)384 * ZLD);
    size_t bcat_o = alloc(ZLD);
    size_t zxb_o  = alloc((size_t)9216 * ZLD);   // reused as mres after K8
    size_t dtv_o  = alloc((size_t)NBH * LL);
    size_t rrv_o  = alloc((size_t)NBH * LL);
    size_t dhv_o  = alloc((size_t)NBH * LL);
    size_t cum_o  = alloc((size_t)NBH * LL);
    size_t Hc_o   = alloc((size_t)NCHUNK * NBH * 16 * PP);
    size_t Rc_o   = alloc((size_t)NCHUNK * NBH);
    size_t h0_o   = alloc((size_t)NCHUNK * NBH * 16 * PP);
    size_t yD_o   = alloc((size_t)9216 * EE);
    size_t g_o    = alloc((size_t)9216 * EE);
    size_t mrg_o  = alloc((size_t)LL * EE);
    size_t outT_o = alloc((size_t)LL * DIMC);

    float* xseq = ws + xseq_o;
    float* proj = ws + proj_o;
    float* xact = ws + xact_o;
    float* wcat = ws + wcat_o;
    float* bcat = ws + bcat_o;
    float* zxb  = ws + zxb_o;
    float* dtv  = ws + dtv_o;
    float* rrv  = ws + rrv_o;
    float* dhv  = ws + dhv_o;
    float* cum  = ws + cum_o;
    float* Hc   = ws + Hc_o;
    float* Rc   = ws + Rc_o;
    float* h0   = ws + h0_o;
    float* yD   = ws + yD_o;
    float* g    = ws + g_o;
    float* mrg  = ws + mrg_o;
    float* outT = ws + outT_o;
    float* btct = xseq;   // alias (same size, disjoint lifetime)
    float* xh   = xact;   // alias
    float* mres = zxb;    // alias

    // 1. build x_seq
    k_build_xseq<<<(KK * LL * DIMC + 255) / 256, 256, 0, stream>>>(x, xseq);
    // 2. prep concat weights
    k_prep_w<<<(EE * ZLD + 255) / 256, 256, 0, stream>>>(w_zx, w_bc, b_bc, w_dt, dt_bias, wcat, bcat);
    // 3. proj = xseq @ w_in  (9216 x 768 x 192)
    gemm_f32<<<dim3(768 / 128, 9216 / 128), 256, 0, stream>>>(xseq, w_in, nullptr, proj,
                                                              9216, 768, 192, 768, 768);
    // 4. xact = silu(proj[:, :384])
    k_act<<<(9216 * 384 + 255) / 256, 256, 0, stream>>>(proj, xact);
    // 5. zx|bc|dt = xact @ wcat + bcat  (9216 x 806 x 384)
    gemm_f32<<<dim3((ZN + 127) / 128, 9216 / 128), 256, 0, stream>>>(xact, wcat, bcat, zxb,
                                                                     9216, ZN, 384, ZLD, ZLD);
    // 6. dt / r / dh
    k_dtr<<<(NBH * LL + 255) / 256, 256, 0, stream>>>(zxb, A_log, dtv, rrv, dhv);
    // 7. cumsum over l
    k_cumsum<<<NBH, 256, 0, stream>>>(dtv, cum);
    // 8. rotate B/C
    k_rot<<<(BK_SEQ * LL + 255) / 256, 256, 0, stream>>>(zxb, cum, theta, btct);
    // 9. pack xh
    k_pack_xh<<<(NBH * LL * PP + 255) / 256, 256, 0, stream>>>(zxb, xh);
    // 10-12. chunked scan
    k_scan_phase<<<dim3(NCHUNK, NBH), 64, 0, stream>>>(btct, rrv, dhv, xh, h0, Hc, Rc, yD, D_skip, 0);
    k_scan_combine<<<NBH, 64, 0, stream>>>(Hc, Rc, h0);
    k_scan_phase<<<dim3(NCHUNK, NBH), 64, 0, stream>>>(btct, rrv, dhv, xh, h0, Hc, Rc, yD, D_skip, 1);
    // 13. g = rms(y*silu(z))*rms_w
    k_gmul<<<9216, 128, 0, stream>>>(yD, zxb, rms_w, g);
    // 14. mres = g @ w_mout (9216 x 384 x 384)  [writes into zxb alias]
    gemm_f32<<<dim3(384 / 128, 9216 / 128), 256, 0, stream>>>(g, w_mout, nullptr, mres,
                                                              9216, 384, 384, 384, 384);
    // 15. gate + merge 4 directions -> mergedT (l, e)
    k_merge<<<(LL * EE + 255) / 256, 256, 0, stream>>>(mres, proj, mrg);
    // 16. outT = mergedT @ w_out (2304 x 192 x 384)
    gemm_f32<<<dim3((192 + 127) / 128, 2304 / 128), 256, 0, stream>>>(mrg, w_out, nullptr, outT,
                                                                      2304, 192, 384, 192, 192);
    // 17. layernorm + residual -> output (192, 2304)
    k_ln<<<LL, 64, 0, stream>>>(outT, x, ln_g, ln_b, res_scale, outF);
    (void)in_sizes; (void)n_in; (void)out_size; (void)ws_size;
}

// Round 4
// 554.852 us; speedup vs baseline: 1.1790x; 1.1790x over previous
//
#include <hip/hip_runtime.h>
#include <hip/hip_bf16.h>
#include <math.h>

// ---------------- problem constants ----------------
#define BN   1
#define DIMC 192
#define HI   48
#define WI   48
#define LL   2304          // HI*WI
#define EE   384
#define NN   16
#define PP   64
#define HHH  6
#define HALF 8
#define KK   4
#define BK_SEQ (BN*KK)     // 4
#define NBH  (BK_SEQ*HHH)  // 24
#define CLEN 24
#define NCHUNK 96          // CLEN*NCHUNK == LL
#define ZLD  816           // padded leading dim for zx|bc|dt (806 logical)
#define ZN   806

static __device__ __forceinline__ float siluf(float v) {
    return v / (1.f + expf(-v));
}

// ---------------- K0: build x_seq (4,2304,192) ----------------
__global__ __launch_bounds__(256) void k_build_xseq(const float* __restrict__ x,
                                                    float* __restrict__ xseq) {
    int idx = blockIdx.x * 256 + threadIdx.x;
    if (idx >= KK * LL * DIMC) return;
    int d = idx % DIMC;
    int l = (idx / DIMC) % LL;
    int k = idx / (DIMC * LL);
    int dim = l / 12;
    int pos = (l % 12) * DIMC + d;   // in [0,2304)
    int src;
    if (k == 0)      src = pos;
    else if (k == 1) src = (pos % 48) * 48 + pos / 48;
    else if (k == 2) src = 2303 - pos;
    else { int p2 = 2303 - pos; src = (p2 % 48) * 48 + p2 / 48; }
    xseq[idx] = x[dim * LL + src];
}

// ---------------- Kprep: concat weights w_zx|w_bc|w_dt and bias ----------------
__global__ __launch_bounds__(256) void k_prep_w(const float* __restrict__ w_zx,
                                                const float* __restrict__ w_bc,
                                                const float* __restrict__ b_bc,
                                                const float* __restrict__ w_dt,
                                                const float* __restrict__ dt_bias,
                                                float* __restrict__ wcat,
                                                float* __restrict__ bcat) {
    int idx = blockIdx.x * 256 + threadIdx.x;
    if (idx < EE * ZLD) {
        int k = idx / ZLD, j = idx % ZLD;
        float v = 0.f;
        if (j < 768)      v = w_zx[k * 768 + j];
        else if (j < 800) v = w_bc[k * 32 + (j - 768)];
        else if (j < ZN)  v = w_dt[k * 6 + (j - 800)];
        wcat[idx] = v;
    }
    if (idx < ZLD) {
        float bv = 0.f;
        if (idx >= 768 && idx < 800) bv = b_bc[idx - 768];
        else if (idx >= 800 && idx < ZN) bv = dt_bias[idx - 800];
        bcat[idx] = bv;
    }
}

// ---------------- generic fp32 GEMM: C = A(MxK,lda) * B(KxN,ldb) (+bias, opt silu on A) ----
// M % 128 == 0, K % 16 == 0 assumed. N guarded.
__global__ __launch_bounds__(256) void gemm_f32(const float* __restrict__ A,
                                                const float* __restrict__ B,
                                                const float* __restrict__ bias,
                                                float* __restrict__ C,
                                                int M, int N, int K,
                                                int lda, int ldb, int ldc, int act) {
    const int BM = 128, BNt = 128, BKt = 16;
    __shared__ float As[BKt][BM + 4];
    __shared__ float Bs[BKt][BNt + 4];
    int bm = blockIdx.y * BM, bn = blockIdx.x * BNt;
    int tid = threadIdx.x;
    int tx = tid & 15, ty = tid >> 4;
    float acc[8][8];
#pragma unroll
    for (int i = 0; i < 8; i++)
#pragma unroll
        for (int j = 0; j < 8; j++) acc[i][j] = 0.f;

    for (int k0 = 0; k0 < K; k0 += BKt) {
        {
            int m = tid >> 1;
            int ks = (tid & 1) * 8;
            const float* ap = A + (size_t)(bm + m) * lda + k0 + ks;
#pragma unroll
            for (int j = 0; j < 8; j++) {
                float v = ap[j];
                if (act) v = siluf(v);
                As[ks + j][m] = v;
            }
        }
        {
            int kk = tid >> 4;
            int ns = (tid & 15) * 8;
            const float* bp = B + (size_t)(k0 + kk) * ldb + bn + ns;
#pragma unroll
            for (int j = 0; j < 8; j++)
                Bs[kk][ns + j] = (bn + ns + j < N) ? bp[j] : 0.f;
        }
        __syncthreads();
#pragma unroll
        for (int kk = 0; kk < BKt; kk++) {
            float a[8], b[8];
#pragma unroll
            for (int i = 0; i < 8; i++) a[i] = As[kk][ty * 8 + i];
#pragma unroll
            for (int j = 0; j < 8; j++) b[j] = Bs[kk][tx * 8 + j];
#pragma unroll
            for (int i = 0; i < 8; i++)
#pragma unroll
                for (int j = 0; j < 8; j++) acc[i][j] += a[i] * b[j];
        }
        __syncthreads();
    }
#pragma unroll
    for (int i = 0; i < 8; i++) {
        int m = bm + ty * 8 + i;
#pragma unroll
        for (int j = 0; j < 8; j++) {
            int n = bn + tx * 8 + j;
            if (n < N) {
                float v = acc[i][j];
                if (bias) v += bias[n];
                C[(size_t)m * ldc + n] = v;
            }
        }
    }
}

// ---------------- K3+K4: softplus/r + cumsum of dt over l, per (bh) ----------------
__global__ __launch_bounds__(256) void k_dtcum(const float* __restrict__ zxb,
                                               const float* __restrict__ A_log,
                                               float* __restrict__ dtv,
                                               float* __restrict__ rrv,
                                               float* __restrict__ cum) {
    int bh = blockIdx.x;
    int tid = threadIdx.x;
    int b = bh / HHH, h = bh % HHH;
    float aexp = expf(A_log[h]);
    const int PER = 9;                    // 256*9 = 2304
    int base = tid * PER;
    float p[PER];
    float s = 0.f;
#pragma unroll
    for (int j = 0; j < PER; j++) {
        int l = base + j;
        float xv = zxb[((size_t)b * LL + l) * ZLD + 800 + h];
        float sp = fmaxf(xv, 0.f) + log1pf(expf(-fabsf(xv)));   // softplus
        dtv[(size_t)bh * LL + l] = sp;
        rrv[(size_t)bh * LL + l] = expf(-sp * aexp);
        s += sp; p[j] = s;
    }
    __shared__ float sh[256];
    sh[tid] = s;
    __syncthreads();
    for (int off = 1; off < 256; off <<= 1) {
        float t = (tid >= off) ? sh[tid - off] : 0.f;
        __syncthreads();
        sh[tid] += t;
        __syncthreads();
    }
    float excl = sh[tid] - s;
#pragma unroll
    for (int j = 0; j < PER; j++) cum[(size_t)bh * LL + base + j] = excl + p[j];
}

// ---------------- K5: RMS-normalize B/C and rotate -> btct (bh, l, 32) ----------------
__global__ __launch_bounds__(256) void k_rot(const float* __restrict__ zxb,
                                             const float* __restrict__ cum,
                                             const float* __restrict__ theta,
                                             float* __restrict__ btct) {
    int idx = blockIdx.x * 256 + threadIdx.x;
    if (idx >= BK_SEQ * LL) return;
    int b = idx / LL, l = idx % LL;
    const float* bcrow = zxb + ((size_t)b * LL + l) * ZLD + 768;
    float Bm[16], Cm[16];
    float sb = 0.f, sc = 0.f;
#pragma unroll
    for (int j = 0; j < 16; j++) {
        Bm[j] = bcrow[j];      sb += Bm[j] * Bm[j];
        Cm[j] = bcrow[16 + j]; sc += Cm[j] * Cm[j];
    }
    float rb = rsqrtf(sb * (1.f / 16.f) + 1e-6f);
    float rc = rsqrtf(sc * (1.f / 16.f) + 1e-6f);
#pragma unroll
    for (int h = 0; h < HHH; h++) {
        float cd = cum[((size_t)b * HHH + h) * LL + l];
        float* out = btct + (((size_t)b * HHH + h) * LL + l) * 32;
#pragma unroll
        for (int j = 0; j < 8; j++) {
            float ang = cd * theta[h * 8 + j];
            float cc = cosf(ang), ss = sinf(ang);
            float b0 = Bm[2 * j] * rb, b1 = Bm[2 * j + 1] * rb;
            out[2 * j]     = b0 * cc + b1 * ss;
            out[2 * j + 1] = -b0 * ss + b1 * cc;
            float c0 = Cm[2 * j] * rc, c1 = Cm[2 * j + 1] * rc;
            out[16 + 2 * j]     = c0 * cc + c1 * ss;
            out[16 + 2 * j + 1] = -c0 * ss + c1 * cc;
        }
    }
}

// ---------------- scan phases A (MODE 0) and C (MODE 1) ----------------
// one wave per (chunk, bh); lane = p. LDS-staged btct/r/dt; xh preloaded to regs.
template <int MODE>
__global__ __launch_bounds__(64) void k_scan_phase(const float* __restrict__ btct,
                                                   const float* __restrict__ rrv,
                                                   const float* __restrict__ dtv,
                                                   const float* __restrict__ zxb,
                                                   const float* __restrict__ h0,
                                                   float* __restrict__ Hc,
                                                   float* __restrict__ Rc,
                                                   float* __restrict__ yD,
                                                   const float* __restrict__ Dsk) {
    int chunk = blockIdx.x;   // 0..NCHUNK-1
    int bh = blockIdx.y;      // 0..NBH-1
    int lane = threadIdx.x;   // p
    int b = bh / HHH, h = bh % HHH;
    int t0 = chunk * CLEN;

    __shared__ float sbt[(CLEN + 1) * 32];   // rows t0-1 .. t0+CLEN-1
    __shared__ float srd[2 * CLEN];          // r | 0.5*dt

    const float* bt_row = btct + (size_t)bh * LL * 32;
    // stage btct rows (float4-coalesced)
    for (int i = lane; i < (CLEN + 1) * 8; i += 64) {
        int t = t0 - 1 + (i >> 3);
        float4 v = make_float4(0.f, 0.f, 0.f, 0.f);
        if (t >= 0)
            v = ((const float4*)(bt_row + (size_t)t * 32))[i & 7];
        ((float4*)sbt)[i] = v;
    }
    if (lane < CLEN) {
        srd[lane] = rrv[(size_t)bh * LL + t0 + lane];
        srd[CLEN + lane] = 0.5f * dtv[(size_t)bh * LL + t0 + lane];
    }

    // per-lane xh column straight out of zxb (coalesced 256B/wave per row)
    const float* xcol = zxb + (size_t)b * LL * ZLD + EE + h * PP + lane;
    float xr[CLEN];
#pragma unroll
    for (int j = 0; j < CLEN; j++) xr[j] = xcol[(size_t)(t0 + j) * ZLD];
    float xprev = (t0 > 0) ? xcol[(size_t)(t0 - 1) * ZLD] : 0.f;

    float hreg[16];
    if (MODE == 0) {
#pragma unroll
        for (int n = 0; n < 16; n++) hreg[n] = 0.f;
    } else {
        const float* hp = h0 + ((size_t)(chunk * NBH + bh) * 16) * PP + lane;
#pragma unroll
        for (int n = 0; n < 16; n++) hreg[n] = hp[n * PP];
    }
    float dsk = (MODE == 1) ? Dsk[h] : 0.f;
    __syncthreads();

    float Btp[16];
#pragma unroll
    for (int n = 0; n < 16; n++) Btp[n] = sbt[n];   // row t0-1 (zeros for chunk 0)
    float Rprod = 1.f;

#pragma unroll
    for (int j = 0; j < CLEN; j++) {
        float r = srd[j];
        float dhalf = srd[CLEN + j];
        float xcur = xr[j];
        const float* bb = sbt + (j + 1) * 32;
        float a = dhalf * xcur;
        float ap = dhalf * r * xprev;
        float y = 0.f;
#pragma unroll
        for (int n = 0; n < 16; n++) {
            float Btn = bb[n];
            hreg[n] = r * hreg[n] + a * Btn + ap * Btp[n];
            Btp[n] = Btn;
            if (MODE) y += bb[16 + n] * hreg[n];
        }
        xprev = xcur;
        if (MODE) {
            yD[((size_t)b * LL + t0 + j) * EE + h * PP + lane] = y + dsk * xcur;
        } else {
            Rprod *= r;
        }
    }
    if (MODE == 0) {
        float* Hp = Hc + ((size_t)(chunk * NBH + bh) * 16) * PP + lane;
#pragma unroll
        for (int n = 0; n < 16; n++) Hp[n * PP] = hreg[n];
        if (lane == 0) Rc[chunk * NBH + bh] = Rprod;
    }
}

// ---------------- scan phase B: combine chunk summaries ----------------
__global__ __launch_bounds__(64) void k_scan_combine(const float* __restrict__ Hc,
                                                     const float* __restrict__ Rc,
                                                     float* __restrict__ h0) {
    int bh = blockIdx.x;
    int lane = threadIdx.x;
    float s[16];
#pragma unroll
    for (int n = 0; n < 16; n++) s[n] = 0.f;
    float* out0 = h0 + ((size_t)(0 * NBH + bh) * 16) * PP + lane;
#pragma unroll
    for (int n = 0; n < 16; n++) out0[n * PP] = 0.f;
    for (int c = 0; c < NCHUNK - 1; ++c) {
        float R = Rc[c * NBH + bh];
        const float* Hp = Hc + ((size_t)(c * NBH + bh) * 16) * PP + lane;
        float* op = h0 + ((size_t)((c + 1) * NBH + bh) * 16) * PP + lane;
#pragma unroll
        for (int n = 0; n < 16; n++) {
            s[n] = R * s[n] + Hp[n * PP];
            op[n * PP] = s[n];
        }
    }
}

// ---------------- K8: g = rms(y * silu(z)) * rms_w ----------------
__global__ __launch_bounds__(128) void k_gmul(const float* __restrict__ yD,
                                              const float* __restrict__ zxb,
                                              const float* __restrict__ rms_w,
                                              float* __restrict__ g) {
    int row = blockIdx.x;
    int tid = threadIdx.x;
    int lane = tid & 63, wid = tid >> 6;
    float v[3];
    float ss = 0.f;
#pragma unroll
    for (int j = 0; j < 3; j++) {
        int e = tid * 3 + j;
        float y = yD[(size_t)row * EE + e];
        float z = zxb[(size_t)row * ZLD + e];
        v[j] = y * siluf(z);
        ss += v[j] * v[j];
    }
#pragma unroll
    for (int off = 1; off < 64; off <<= 1) ss += __shfl_xor(ss, off);
    __shared__ float red[2];
    if (lane == 0) red[wid] = ss;
    __syncthreads();
    float total = red[0] + red[1];
    float scale = rsqrtf(total * (1.f / (float)EE) + 1e-6f);
#pragma unroll
    for (int j = 0; j < 3; j++) {
        int e = tid * 3 + j;
        g[(size_t)row * EE + e] = v[j] * scale * rms_w[e];
    }
}

// ---------------- K9: gate + 4-direction merge -> mergedT (l, e) ----------------
__global__ __launch_bounds__(256) void k_merge(const float* __restrict__ mres,
                                               const float* __restrict__ proj,
                                               float* __restrict__ mrg) {
    int idx = blockIdx.x * 256 + threadIdx.x;
    if (idx >= LL * EE) return;
    int e = idx % EE, l = idx / EE;
    int l1 = (l % 48) * 48 + l / 48;
    int rows[4];
    rows[0] = 0 * LL + l;
    rows[1] = 1 * LL + l1;
    rows[2] = 2 * LL + (2303 - l);
    rows[3] = 3 * LL + (2303 - l1);
    float acc = 0.f;
#pragma unroll
    for (int k = 0; k < 4; k++) {
        float m = mres[(size_t)rows[k] * EE + e];
        float gz = proj[(size_t)rows[k] * 768 + EE + e];
        acc += m * siluf(gz);
    }
    mrg[idx] = acc;
}

// ---------------- K10: LayerNorm over channels + residual ----------------
__global__ __launch_bounds__(64) void k_ln(const float* __restrict__ outT,
                                           const float* __restrict__ x,
                                           const float* __restrict__ ln_g,
                                           const float* __restrict__ ln_b,
                                           const float* __restrict__ res_scale,
                                           float* __restrict__ outF) {
    int l = blockIdx.x;
    int lane = threadIdx.x;
    float v[3];
    float s = 0.f;
#pragma unroll
    for (int j = 0; j < 3; j++) {
        int d = lane * 3 + j;
        v[j] = outT[(size_t)l * DIMC + d];
        s += v[j];
    }
#pragma unroll
    for (int off = 1; off < 64; off <<= 1) s += __shfl_xor(s, off);
    float mu = s * (1.f / (float)DIMC);
    float sq = 0.f;
#pragma unroll
    for (int j = 0; j < 3; j++) { float dlt = v[j] - mu; sq += dlt * dlt; }
#pragma unroll
    for (int off = 1; off < 64; off <<= 1) sq += __shfl_xor(sq, off);
    float rstd = rsqrtf(sq * (1.f / (float)DIMC) + 1e-5f);
    float rs = res_scale[0];
#pragma unroll
    for (int j = 0; j < 3; j++) {
        int d = lane * 3 + j;
        outF[(size_t)d * LL + l] =
            x[(size_t)d * LL + l] + rs * ((v[j] - mu) * rstd * ln_g[d] + ln_b[d]);
    }
}

// ---------------- host launcher ----------------
extern "C" void kernel_launch(void* const* d_in, const int* in_sizes, int n_in,
                              void* d_out, int out_size, void* d_ws, size_t ws_size,
                              hipStream_t stream) {
    const float* x        = (const float*)d_in[0];
    const float* w_in     = (const float*)d_in[1];
    const float* w_zx     = (const float*)d_in[2];
    const float* w_bc     = (const float*)d_in[3];
    const float* b_bc     = (const float*)d_in[4];
    const float* w_dt     = (const float*)d_in[5];
    const float* dt_bias  = (const float*)d_in[6];
    const float* A_log    = (const float*)d_in[7];
    const float* theta    = (const float*)d_in[8];
    const float* D_skip   = (const float*)d_in[9];
    const float* rms_w    = (const float*)d_in[10];
    const float* w_mout   = (const float*)d_in[11];
    const float* w_out    = (const float*)d_in[12];
    const float* ln_g     = (const float*)d_in[13];
    const float* ln_b     = (const float*)d_in[14];
    const float* res_scale= (const float*)d_in[15];
    float* outF = (float*)d_out;
    float* ws = (float*)d_ws;

    // workspace layout (floats), with aliasing
    size_t o = 0;
    auto alloc = [&](size_t n) { size_t r = o; o += (n + 127) & ~(size_t)127; return r; };
    size_t xseq_o = alloc(1769472);              // reused as btct after proj GEMM
    size_t proj_o = alloc((size_t)9216 * 768);
    size_t wcat_o = alloc((size_t)384 * ZLD);
    size_t bcat_o = alloc(ZLD);
    size_t zxb_o  = alloc((size_t)9216 * ZLD);   // reused as mres after k_gmul
    size_t dtv_o  = alloc((size_t)NBH * LL);
    size_t rrv_o  = alloc((size_t)NBH * LL);
    size_t cum_o  = alloc((size_t)NBH * LL);
    size_t Hc_o   = alloc((size_t)NCHUNK * NBH * 16 * PP);
    size_t Rc_o   = alloc((size_t)NCHUNK * NBH);
    size_t h0_o   = alloc((size_t)NCHUNK * NBH * 16 * PP);
    size_t yD_o   = alloc((size_t)9216 * EE);
    size_t g_o    = alloc((size_t)9216 * EE);
    size_t mrg_o  = alloc((size_t)LL * EE);
    size_t outT_o = alloc((size_t)LL * DIMC);

    float* xseq = ws + xseq_o;
    float* proj = ws + proj_o;
    float* wcat = ws + wcat_o;
    float* bcat = ws + bcat_o;
    float* zxb  = ws + zxb_o;
    float* dtv  = ws + dtv_o;
    float* rrv  = ws + rrv_o;
    float* cum  = ws + cum_o;
    float* Hc   = ws + Hc_o;
    float* Rc   = ws + Rc_o;
    float* h0   = ws + h0_o;
    float* yD   = ws + yD_o;
    float* g    = ws + g_o;
    float* mrg  = ws + mrg_o;
    float* outT = ws + outT_o;
    float* btct = xseq;   // alias (disjoint lifetime: xseq dead after proj GEMM)
    float* mres = zxb;    // alias (zxb dead after k_gmul)

    // 1. build x_seq
    k_build_xseq<<<(KK * LL * DIMC + 255) / 256, 256, 0, stream>>>(x, xseq);
    // 2. prep concat weights
    k_prep_w<<<(EE * ZLD + 255) / 256, 256, 0, stream>>>(w_zx, w_bc, b_bc, w_dt, dt_bias, wcat, bcat);
    // 3. proj = xseq @ w_in  (9216 x 768 x 192)
    gemm_f32<<<dim3(768 / 128, 9216 / 128), 256, 0, stream>>>(xseq, w_in, nullptr, proj,
                                                              9216, 768, 192, 192, 768, 768, 0);
    // 4. zx|bc|dt = silu(proj[:, :384]) @ wcat + bcat  (9216 x 806 x 384, silu fused)
    gemm_f32<<<dim3((ZN + 127) / 128, 9216 / 128), 256, 0, stream>>>(proj, wcat, bcat, zxb,
                                                                     9216, ZN, 384, 768, ZLD, ZLD, 1);
    // 5. dt / r / cumsum
    k_dtcum<<<NBH, 256, 0, stream>>>(zxb, A_log, dtv, rrv, cum);
    // 6. rotate B/C
    k_rot<<<(BK_SEQ * LL + 255) / 256, 256, 0, stream>>>(zxb, cum, theta, btct);
    // 7-9. chunked scan
    k_scan_phase<0><<<dim3(NCHUNK, NBH), 64, 0, stream>>>(btct, rrv, dtv, zxb, h0, Hc, Rc, yD, D_skip);
    k_scan_combine<<<NBH, 64, 0, stream>>>(Hc, Rc, h0);
    k_scan_phase<1><<<dim3(NCHUNK, NBH), 64, 0, stream>>>(btct, rrv, dtv, zxb, h0, Hc, Rc, yD, D_skip);
    // 10. g = rms(y*silu(z))*rms_w
    k_gmul<<<9216, 128, 0, stream>>>(yD, zxb, rms_w, g);
    // 11. mres = g @ w_mout (9216 x 384 x 384)  [writes into zxb alias]
    gemm_f32<<<dim3(384 / 128, 9216 / 128), 256, 0, stream>>>(g, w_mout, nullptr, mres,
                                                              9216, 384, 384, 384, 384, 384, 0);
    // 12. gate + merge 4 directions -> mergedT (l, e)
    k_merge<<<(LL * EE + 255) / 256, 256, 0, stream>>>(mres, proj, mrg);
    // 13. outT = mergedT @ w_out (2304 x 192 x 384)
    gemm_f32<<<dim3((192 + 127) / 128, 2304 / 128), 256, 0, stream>>>(mrg, w_out, nullptr, outT,
                                                                      2304, 192, 384, 384, 192, 192, 0);
    // 14. layernorm + residual -> output (192, 2304)
    k_ln<<<LL, 64, 0, stream>>>(outT, x, ln_g, ln_b, res_scale, outF);
    (void)in_sizes; (void)n_in; (void)out_size; (void)ws_size;
}

// Round 5
// 362.879 us; speedup vs baseline: 1.8027x; 1.5290x over previous
//
#include <hip/hip_runtime.h>
#include <hip/hip_bf16.h>
#include <math.h>

// ---------------- problem constants ----------------
#define BN   1
#define DIMC 192
#define HI   48
#define WI   48
#define LL   2304          // HI*WI
#define EE   384
#define NN   16
#define PP   64
#define HHH  6
#define HALF 8
#define KK   4
#define BK_SEQ (BN*KK)     // 4
#define NBH  (BK_SEQ*HHH)  // 24
#define CLEN 24
#define NCHUNK 96          // CLEN*NCHUNK == LL
#define ZLD  816           // padded leading dim for zx|bc|dt (806 logical)
#define ZN   806

static __device__ __forceinline__ float siluf(float v) {
    return v / (1.f + expf(-v));
}

// ---------------- K0: build x_seq (4,2304,192) ----------------
__global__ __launch_bounds__(256) void k_build_xseq(const float* __restrict__ x,
                                                    float* __restrict__ xseq) {
    int idx = blockIdx.x * 256 + threadIdx.x;
    if (idx >= KK * LL * DIMC) return;
    int d = idx % DIMC;
    int l = (idx / DIMC) % LL;
    int k = idx / (DIMC * LL);
    int dim = l / 12;
    int pos = (l % 12) * DIMC + d;   // in [0,2304)
    int src;
    if (k == 0)      src = pos;
    else if (k == 1) src = (pos % 48) * 48 + pos / 48;
    else if (k == 2) src = 2303 - pos;
    else { int p2 = 2303 - pos; src = (p2 % 48) * 48 + p2 / 48; }
    xseq[idx] = x[dim * LL + src];
}

// ---------------- Kprep: concat weights w_zx|w_bc|w_dt and bias ----------------
__global__ __launch_bounds__(256) void k_prep_w(const float* __restrict__ w_zx,
                                                const float* __restrict__ w_bc,
                                                const float* __restrict__ b_bc,
                                                const float* __restrict__ w_dt,
                                                const float* __restrict__ dt_bias,
                                                float* __restrict__ wcat,
                                                float* __restrict__ bcat) {
    int idx = blockIdx.x * 256 + threadIdx.x;
    if (idx < EE * ZLD) {
        int k = idx / ZLD, j = idx % ZLD;
        float v = 0.f;
        if (j < 768)      v = w_zx[k * 768 + j];
        else if (j < 800) v = w_bc[k * 32 + (j - 768)];
        else if (j < ZN)  v = w_dt[k * 6 + (j - 800)];
        wcat[idx] = v;
    }
    if (idx < ZLD) {
        float bv = 0.f;
        if (idx >= 768 && idx < 800) bv = b_bc[idx - 768];
        else if (idx >= 800 && idx < ZN) bv = dt_bias[idx - 800];
        bcat[idx] = bv;
    }
}

// ---------------- tiled fp32 GEMM: C = A(MxK,lda) * B(KxN,ldb) (+bias, opt silu on A) ----
// 256 threads. Per-thread TMxTN spread as 4-wide quadrant sub-blocks so all LDS
// accesses are aligned float4 (ds_read_b128) with <=2-way bank aliasing (free).
// Requires: M % BM == 0, K % 16 == 0. N guarded.
template <int BM, int BNt, int TM, int TN>
__global__ __launch_bounds__(256) void gemm_f32t(const float* __restrict__ A,
                                                 const float* __restrict__ B,
                                                 const float* __restrict__ bias,
                                                 float* __restrict__ C,
                                                 int M, int N, int K,
                                                 int lda, int ldb, int ldc, int act) {
    constexpr int BKt = 16;
    constexpr int NTX = BNt / TN;            // threads along N
    constexpr int NTY = BM / TM;             // threads along M
    static_assert(NTX * NTY == 256, "need 256 threads");
    constexpr int QM = TM / 4;               // 1 or 2 quadrant sub-blocks (rows)
    constexpr int QN = TN / 4;               // 1 or 2 quadrant sub-blocks (cols)
    constexpr int PAD = 4;
    __shared__ float As[BKt][BM + PAD];
    __shared__ float Bs[BKt][BNt + PAD];

    int bm = blockIdx.y * BM, bn = blockIdx.x * BNt;
    int tid = threadIdx.x;
    int tx = tid % NTX, ty = tid / NTX;

    float acc[TM][TN];
#pragma unroll
    for (int i = 0; i < TM; i++)
#pragma unroll
        for (int j = 0; j < TN; j++) acc[i][j] = 0.f;

    for (int k0 = 0; k0 < K; k0 += BKt) {
        // stage A (BM x 16), transposed into As[k][m]
        constexpr int FA = (BM * BKt) / (256 * 4);   // float4 loads per thread
#pragma unroll
        for (int p = 0; p < FA; ++p) {
            int fid = p * 256 + tid;
            int r = fid >> 2;                 // 4 float4 per 16-float row
            int c4 = (fid & 3) * 4;
            const float* ap = A + (size_t)(bm + r) * lda + k0 + c4;
            float4 v = *(const float4*)ap;
            if (act) { v.x = siluf(v.x); v.y = siluf(v.y); v.z = siluf(v.z); v.w = siluf(v.w); }
            As[c4 + 0][r] = v.x;
            As[c4 + 1][r] = v.y;
            As[c4 + 2][r] = v.z;
            As[c4 + 3][r] = v.w;
        }
        // stage B (16 x BNt) row-major
        constexpr int FB = (BKt * BNt) / (256 * 4);
#pragma unroll
        for (int p = 0; p < FB; ++p) {
            int fid = p * 256 + tid;
            int kk = fid / (BNt / 4);
            int c4 = (fid % (BNt / 4)) * 4;
            int cc = bn + c4;
            const float* bp = B + (size_t)(k0 + kk) * ldb + cc;
            float4 v;
            if (cc + 4 <= N) {
                v = *(const float4*)bp;
            } else {
                v.x = (cc + 0 < N) ? bp[0] : 0.f;
                v.y = (cc + 1 < N) ? bp[1] : 0.f;
                v.z = (cc + 2 < N) ? bp[2] : 0.f;
                v.w = (cc + 3 < N) ? bp[3] : 0.f;
            }
            *(float4*)&Bs[kk][c4] = v;
        }
        __syncthreads();
#pragma unroll
        for (int kk = 0; kk < BKt; kk++) {
            float av[QM * 4], bv[QN * 4];
#pragma unroll
            for (int qi = 0; qi < QM; qi++)
                *(float4*)&av[qi * 4] = *(const float4*)&As[kk][qi * (BM / 2) + ty * 4];
#pragma unroll
            for (int qj = 0; qj < QN; qj++)
                *(float4*)&bv[qj * 4] = *(const float4*)&Bs[kk][qj * (BNt / 2) + tx * 4];
#pragma unroll
            for (int i = 0; i < TM; i++)
#pragma unroll
                for (int j = 0; j < TN; j++)
                    acc[i][j] += av[i] * bv[j];
        }
        __syncthreads();
    }
    // epilogue
#pragma unroll
    for (int qi = 0; qi < QM; qi++) {
#pragma unroll
        for (int i = 0; i < 4; i++) {
            int m = bm + qi * (BM / 2) + ty * 4 + i;
#pragma unroll
            for (int qj = 0; qj < QN; qj++) {
                int cc = bn + qj * (BNt / 2) + tx * 4;
                float4 v;
                v.x = acc[qi * 4 + i][qj * 4 + 0];
                v.y = acc[qi * 4 + i][qj * 4 + 1];
                v.z = acc[qi * 4 + i][qj * 4 + 2];
                v.w = acc[qi * 4 + i][qj * 4 + 3];
                if (bias) {
                    v.x += (cc + 0 < N) ? bias[cc + 0] : 0.f;
                    v.y += (cc + 1 < N) ? bias[cc + 1] : 0.f;
                    v.z += (cc + 2 < N) ? bias[cc + 2] : 0.f;
                    v.w += (cc + 3 < N) ? bias[cc + 3] : 0.f;
                }
                float* cp = C + (size_t)m * ldc + cc;
                if (cc + 4 <= N) {
                    *(float4*)cp = v;
                } else {
                    if (cc + 0 < N) cp[0] = v.x;
                    if (cc + 1 < N) cp[1] = v.y;
                    if (cc + 2 < N) cp[2] = v.z;
                    if (cc + 3 < N) cp[3] = v.w;
                }
            }
        }
    }
}

// ---------------- K3+K4: softplus/r + cumsum of dt over l, per (bh) ----------------
__global__ __launch_bounds__(256) void k_dtcum(const float* __restrict__ zxb,
                                               const float* __restrict__ A_log,
                                               float* __restrict__ dtv,
                                               float* __restrict__ rrv,
                                               float* __restrict__ cum) {
    int bh = blockIdx.x;
    int tid = threadIdx.x;
    int b = bh / HHH, h = bh % HHH;
    float aexp = expf(A_log[h]);
    const int PER = 9;                    // 256*9 = 2304
    int base = tid * PER;
    float p[PER];
    float s = 0.f;
#pragma unroll
    for (int j = 0; j < PER; j++) {
        int l = base + j;
        float xv = zxb[((size_t)b * LL + l) * ZLD + 800 + h];
        float sp = fmaxf(xv, 0.f) + log1pf(expf(-fabsf(xv)));   // softplus
        dtv[(size_t)bh * LL + l] = sp;
        rrv[(size_t)bh * LL + l] = expf(-sp * aexp);
        s += sp; p[j] = s;
    }
    __shared__ float sh[256];
    sh[tid] = s;
    __syncthreads();
    for (int off = 1; off < 256; off <<= 1) {
        float t = (tid >= off) ? sh[tid - off] : 0.f;
        __syncthreads();
        sh[tid] += t;
        __syncthreads();
    }
    float excl = sh[tid] - s;
#pragma unroll
    for (int j = 0; j < PER; j++) cum[(size_t)bh * LL + base + j] = excl + p[j];
}

// ---------------- K5: RMS-normalize B/C and rotate -> btct (bh, l, 32) ----------------
__global__ __launch_bounds__(256) void k_rot(const float* __restrict__ zxb,
                                             const float* __restrict__ cum,
                                             const float* __restrict__ theta,
                                             float* __restrict__ btct) {
    int idx = blockIdx.x * 256 + threadIdx.x;
    if (idx >= BK_SEQ * LL) return;
    int b = idx / LL, l = idx % LL;
    const float* bcrow = zxb + ((size_t)b * LL + l) * ZLD + 768;
    float Bm[16], Cm[16];
    float sb = 0.f, sc = 0.f;
#pragma unroll
    for (int j = 0; j < 16; j++) {
        Bm[j] = bcrow[j];      sb += Bm[j] * Bm[j];
        Cm[j] = bcrow[16 + j]; sc += Cm[j] * Cm[j];
    }
    float rb = rsqrtf(sb * (1.f / 16.f) + 1e-6f);
    float rc = rsqrtf(sc * (1.f / 16.f) + 1e-6f);
#pragma unroll
    for (int h = 0; h < HHH; h++) {
        float cd = cum[((size_t)b * HHH + h) * LL + l];
        float* out = btct + (((size_t)b * HHH + h) * LL + l) * 32;
#pragma unroll
        for (int j = 0; j < 8; j++) {
            float ang = cd * theta[h * 8 + j];
            float cc = cosf(ang), ss = sinf(ang);
            float b0 = Bm[2 * j] * rb, b1 = Bm[2 * j + 1] * rb;
            out[2 * j]     = b0 * cc + b1 * ss;
            out[2 * j + 1] = -b0 * ss + b1 * cc;
            float c0 = Cm[2 * j] * rc, c1 = Cm[2 * j + 1] * rc;
            out[16 + 2 * j]     = c0 * cc + c1 * ss;
            out[16 + 2 * j + 1] = -c0 * ss + c1 * cc;
        }
    }
}

// ---------------- scan phases A (MODE 0) and C (MODE 1) ----------------
// one wave per (chunk, bh); lane = p. LDS-staged btct/r/dt; xh preloaded to regs.
template <int MODE>
__global__ __launch_bounds__(64) void k_scan_phase(const float* __restrict__ btct,
                                                   const float* __restrict__ rrv,
                                                   const float* __restrict__ dtv,
                                                   const float* __restrict__ zxb,
                                                   const float* __restrict__ h0,
                                                   float* __restrict__ Hc,
                                                   float* __restrict__ Rc,
                                                   float* __restrict__ yD,
                                                   const float* __restrict__ Dsk) {
    int chunk = blockIdx.x;   // 0..NCHUNK-1
    int bh = blockIdx.y;      // 0..NBH-1
    int lane = threadIdx.x;   // p
    int b = bh / HHH, h = bh % HHH;
    int t0 = chunk * CLEN;

    __shared__ float sbt[(CLEN + 1) * 32];   // rows t0-1 .. t0+CLEN-1
    __shared__ float srd[2 * CLEN];          // r | 0.5*dt

    const float* bt_row = btct + (size_t)bh * LL * 32;
    // stage btct rows (float4-coalesced)
    for (int i = lane; i < (CLEN + 1) * 8; i += 64) {
        int t = t0 - 1 + (i >> 3);
        float4 v = make_float4(0.f, 0.f, 0.f, 0.f);
        if (t >= 0)
            v = ((const float4*)(bt_row + (size_t)t * 32))[i & 7];
        ((float4*)sbt)[i] = v;
    }
    if (lane < CLEN) {
        srd[lane] = rrv[(size_t)bh * LL + t0 + lane];
        srd[CLEN + lane] = 0.5f * dtv[(size_t)bh * LL + t0 + lane];
    }

    // per-lane xh column straight out of zxb (coalesced 256B/wave per row)
    const float* xcol = zxb + (size_t)b * LL * ZLD + EE + h * PP + lane;
    float xr[CLEN];
#pragma unroll
    for (int j = 0; j < CLEN; j++) xr[j] = xcol[(size_t)(t0 + j) * ZLD];
    float xprev = (t0 > 0) ? xcol[(size_t)(t0 - 1) * ZLD] : 0.f;

    float hreg[16];
    if (MODE == 0) {
#pragma unroll
        for (int n = 0; n < 16; n++) hreg[n] = 0.f;
    } else {
        const float* hp = h0 + ((size_t)(chunk * NBH + bh) * 16) * PP + lane;
#pragma unroll
        for (int n = 0; n < 16; n++) hreg[n] = hp[n * PP];
    }
    float dsk = (MODE == 1) ? Dsk[h] : 0.f;
    __syncthreads();

    float Btp[16];
#pragma unroll
    for (int n = 0; n < 16; n++) Btp[n] = sbt[n];   // row t0-1 (zeros for chunk 0)
    float Rprod = 1.f;

#pragma unroll
    for (int j = 0; j < CLEN; j++) {
        float r = srd[j];
        float dhalf = srd[CLEN + j];
        float xcur = xr[j];
        const float* bb = sbt + (j + 1) * 32;
        float a = dhalf * xcur;
        float ap = dhalf * r * xprev;
        float y = 0.f;
#pragma unroll
        for (int n = 0; n < 16; n++) {
            float Btn = bb[n];
            hreg[n] = r * hreg[n] + a * Btn + ap * Btp[n];
            Btp[n] = Btn;
            if (MODE) y += bb[16 + n] * hreg[n];
        }
        xprev = xcur;
        if (MODE) {
            yD[((size_t)b * LL + t0 + j) * EE + h * PP + lane] = y + dsk * xcur;
        } else {
            Rprod *= r;
        }
    }
    if (MODE == 0) {
        float* Hp = Hc + ((size_t)(chunk * NBH + bh) * 16) * PP + lane;
#pragma unroll
        for (int n = 0; n < 16; n++) Hp[n * PP] = hreg[n];
        if (lane == 0) Rc[chunk * NBH + bh] = Rprod;
    }
}

// ---------------- scan phase B: combine chunk summaries ----------------
__global__ __launch_bounds__(64) void k_scan_combine(const float* __restrict__ Hc,
                                                     const float* __restrict__ Rc,
                                                     float* __restrict__ h0) {
    int bh = blockIdx.x;
    int lane = threadIdx.x;
    float s[16];
#pragma unroll
    for (int n = 0; n < 16; n++) s[n] = 0.f;
    float* out0 = h0 + ((size_t)(0 * NBH + bh) * 16) * PP + lane;
#pragma unroll
    for (int n = 0; n < 16; n++) out0[n * PP] = 0.f;
    for (int c = 0; c < NCHUNK - 1; ++c) {
        float R = Rc[c * NBH + bh];
        const float* Hp = Hc + ((size_t)(c * NBH + bh) * 16) * PP + lane;
        float* op = h0 + ((size_t)((c + 1) * NBH + bh) * 16) * PP + lane;
#pragma unroll
        for (int n = 0; n < 16; n++) {
            s[n] = R * s[n] + Hp[n * PP];
            op[n * PP] = s[n];
        }
    }
}

// ---------------- K8: g = rms(y * silu(z)) * rms_w ----------------
__global__ __launch_bounds__(128) void k_gmul(const float* __restrict__ yD,
                                              const float* __restrict__ zxb,
                                              const float* __restrict__ rms_w,
                                              float* __restrict__ g) {
    int row = blockIdx.x;
    int tid = threadIdx.x;
    int lane = tid & 63, wid = tid >> 6;
    float v[3];
    float ss = 0.f;
#pragma unroll
    for (int j = 0; j < 3; j++) {
        int e = tid * 3 + j;
        float y = yD[(size_t)row * EE + e];
        float z = zxb[(size_t)row * ZLD + e];
        v[j] = y * siluf(z);
        ss += v[j] * v[j];
    }
#pragma unroll
    for (int off = 1; off < 64; off <<= 1) ss += __shfl_xor(ss, off);
    __shared__ float red[2];
    if (lane == 0) red[wid] = ss;
    __syncthreads();
    float total = red[0] + red[1];
    float scale = rsqrtf(total * (1.f / (float)EE) + 1e-6f);
#pragma unroll
    for (int j = 0; j < 3; j++) {
        int e = tid * 3 + j;
        g[(size_t)row * EE + e] = v[j] * scale * rms_w[e];
    }
}

// ---------------- K9: gate + 4-direction merge -> mergedT (l, e) ----------------
__global__ __launch_bounds__(256) void k_merge(const float* __restrict__ mres,
                                               const float* __restrict__ proj,
                                               float* __restrict__ mrg) {
    int idx = blockIdx.x * 256 + threadIdx.x;
    if (idx >= LL * EE) return;
    int e = idx % EE, l = idx / EE;
    int l1 = (l % 48) * 48 + l / 48;
    int rows[4];
    rows[0] = 0 * LL + l;
    rows[1] = 1 * LL + l1;
    rows[2] = 2 * LL + (2303 - l);
    rows[3] = 3 * LL + (2303 - l1);
    float acc = 0.f;
#pragma unroll
    for (int k = 0; k < 4; k++) {
        float m = mres[(size_t)rows[k] * EE + e];
        float gz = proj[(size_t)rows[k] * 768 + EE + e];
        acc += m * siluf(gz);
    }
    mrg[idx] = acc;
}

// ---------------- K10: LayerNorm over channels + residual ----------------
__global__ __launch_bounds__(64) void k_ln(const float* __restrict__ outT,
                                           const float* __restrict__ x,
                                           const float* __restrict__ ln_g,
                                           const float* __restrict__ ln_b,
                                           const float* __restrict__ res_scale,
                                           float* __restrict__ outF) {
    int l = blockIdx.x;
    int lane = threadIdx.x;
    float v[3];
    float s = 0.f;
#pragma unroll
    for (int j = 0; j < 3; j++) {
        int d = lane * 3 + j;
        v[j] = outT[(size_t)l * DIMC + d];
        s += v[j];
    }
#pragma unroll
    for (int off = 1; off < 64; off <<= 1) s += __shfl_xor(s, off);
    float mu = s * (1.f / (float)DIMC);
    float sq = 0.f;
#pragma unroll
    for (int j = 0; j < 3; j++) { float dlt = v[j] - mu; sq += dlt * dlt; }
#pragma unroll
    for (int off = 1; off < 64; off <<= 1) sq += __shfl_xor(sq, off);
    float rstd = rsqrtf(sq * (1.f / (float)DIMC) + 1e-5f);
    float rs = res_scale[0];
#pragma unroll
    for (int j = 0; j < 3; j++) {
        int d = lane * 3 + j;
        outF[(size_t)d * LL + l] =
            x[(size_t)d * LL + l] + rs * ((v[j] - mu) * rstd * ln_g[d] + ln_b[d]);
    }
}

// ---------------- host launcher ----------------
extern "C" void kernel_launch(void* const* d_in, const int* in_sizes, int n_in,
                              void* d_out, int out_size, void* d_ws, size_t ws_size,
                              hipStream_t stream) {
    const float* x        = (const float*)d_in[0];
    const float* w_in     = (const float*)d_in[1];
    const float* w_zx     = (const float*)d_in[2];
    const float* w_bc     = (const float*)d_in[3];
    const float* b_bc     = (const float*)d_in[4];
    const float* w_dt     = (const float*)d_in[5];
    const float* dt_bias  = (const float*)d_in[6];
    const float* A_log    = (const float*)d_in[7];
    const float* theta    = (const float*)d_in[8];
    const float* D_skip   = (const float*)d_in[9];
    const float* rms_w    = (const float*)d_in[10];
    const float* w_mout   = (const float*)d_in[11];
    const float* w_out    = (const float*)d_in[12];
    const float* ln_g     = (const float*)d_in[13];
    const float* ln_b     = (const float*)d_in[14];
    const float* res_scale= (const float*)d_in[15];
    float* outF = (float*)d_out;
    float* ws = (float*)d_ws;

    // workspace layout (floats), with aliasing
    size_t o = 0;
    auto alloc = [&](size_t n) { size_t r = o; o += (n + 127) & ~(size_t)127; return r; };
    size_t xseq_o = alloc(1769472);              // reused as btct after proj GEMM
    size_t proj_o = alloc((size_t)9216 * 768);
    size_t wcat_o = alloc((size_t)384 * ZLD);
    size_t bcat_o = alloc(ZLD);
    size_t zxb_o  = alloc((size_t)9216 * ZLD);   // reused as mres after k_gmul
    size_t dtv_o  = alloc((size_t)NBH * LL);
    size_t rrv_o  = alloc((size_t)NBH * LL);
    size_t cum_o  = alloc((size_t)NBH * LL);
    size_t Hc_o   = alloc((size_t)NCHUNK * NBH * 16 * PP);
    size_t Rc_o   = alloc((size_t)NCHUNK * NBH);
    size_t h0_o   = alloc((size_t)NCHUNK * NBH * 16 * PP);
    size_t yD_o   = alloc((size_t)9216 * EE);
    size_t g_o    = alloc((size_t)9216 * EE);
    size_t mrg_o  = alloc((size_t)LL * EE);
    size_t outT_o = alloc((size_t)LL * DIMC);

    float* xseq = ws + xseq_o;
    float* proj = ws + proj_o;
    float* wcat = ws + wcat_o;
    float* bcat = ws + bcat_o;
    float* zxb  = ws + zxb_o;
    float* dtv  = ws + dtv_o;
    float* rrv  = ws + rrv_o;
    float* cum  = ws + cum_o;
    float* Hc   = ws + Hc_o;
    float* Rc   = ws + Rc_o;
    float* h0   = ws + h0_o;
    float* yD   = ws + yD_o;
    float* g    = ws + g_o;
    float* mrg  = ws + mrg_o;
    float* outT = ws + outT_o;
    float* btct = xseq;   // alias (disjoint lifetime: xseq dead after proj GEMM)
    float* mres = zxb;    // alias (zxb dead after k_gmul)

    // 1. build x_seq
    k_build_xseq<<<(KK * LL * DIMC + 255) / 256, 256, 0, stream>>>(x, xseq);
    // 2. prep concat weights
    k_prep_w<<<(EE * ZLD + 255) / 256, 256, 0, stream>>>(w_zx, w_bc, b_bc, w_dt, dt_bias, wcat, bcat);
    // 3. proj = xseq @ w_in  (9216 x 768 x 192)
    gemm_f32t<128, 128, 8, 8><<<dim3(768 / 128, 9216 / 128), 256, 0, stream>>>(
        xseq, w_in, nullptr, proj, 9216, 768, 192, 192, 768, 768, 0);
    // 4. zx|bc|dt = silu(proj[:, :384]) @ wcat + bcat  (9216 x 806 x 384, silu fused)
    gemm_f32t<128, 128, 8, 8><<<dim3((ZN + 127) / 128, 9216 / 128), 256, 0, stream>>>(
        proj, wcat, bcat, zxb, 9216, ZN, 384, 768, ZLD, ZLD, 1);
    // 5. dt / r / cumsum
    k_dtcum<<<NBH, 256, 0, stream>>>(zxb, A_log, dtv, rrv, cum);
    // 6. rotate B/C
    k_rot<<<(BK_SEQ * LL + 255) / 256, 256, 0, stream>>>(zxb, cum, theta, btct);
    // 7-9. chunked scan
    k_scan_phase<0><<<dim3(NCHUNK, NBH), 64, 0, stream>>>(btct, rrv, dtv, zxb, h0, Hc, Rc, yD, D_skip);
    k_scan_combine<<<NBH, 64, 0, stream>>>(Hc, Rc, h0);
    k_scan_phase<1><<<dim3(NCHUNK, NBH), 64, 0, stream>>>(btct, rrv, dtv, zxb, h0, Hc, Rc, yD, D_skip);
    // 10. g = rms(y*silu(z))*rms_w
    k_gmul<<<9216, 128, 0, stream>>>(yD, zxb, rms_w, g);
    // 11. mres = g @ w_mout (9216 x 384 x 384)  [writes into zxb alias]
    gemm_f32t<64, 128, 4, 8><<<dim3(384 / 128, 9216 / 64), 256, 0, stream>>>(
        g, w_mout, nullptr, mres, 9216, 384, 384, 384, 384, 384, 0);
    // 12. gate + merge 4 directions -> mergedT (l, e)
    k_merge<<<(LL * EE + 255) / 256, 256, 0, stream>>>(mres, proj, mrg);
    // 13. outT = mergedT @ w_out (2304 x 192 x 384)
    gemm_f32t<64, 64, 4, 4><<<dim3(192 / 64, 2304 / 64), 256, 0, stream>>>(
        mrg, w_out, nullptr, outT, 2304, 192, 384, 384, 192, 192, 0);
    // 14. layernorm + residual -> output (192, 2304)
    k_ln<<<LL, 64, 0, stream>>>(outT, x, ln_g, ln_b, res_scale, outF);
    (void)in_sizes; (void)n_in; (void)out_size; (void)ws_size;
}

// Round 7
// 280.300 us; speedup vs baseline: 2.3338x; 1.2946x over previous
//
#include <hip/hip_runtime.h>
#include <hip/hip_bf16.h>
#include <math.h>

// ---------------- problem constants ----------------
#define BN   1
#define DIMC 192
#define HI   48
#define WI   48
#define LL   2304          // HI*WI
#define EE   384
#define NN   16
#define PP   64
#define HHH  6
#define HALF 8
#define KK   4
#define BK_SEQ (BN*KK)     // 4
#define NBH  (BK_SEQ*HHH)  // 24
#define CLEN 24
#define NCHUNK 96          // CLEN*NCHUNK == LL
#define ZLD  816           // padded leading dim for zx|bc|dt (806 logical)
#define ZN   806

typedef __attribute__((ext_vector_type(8))) short bf16x8;
typedef __attribute__((ext_vector_type(4))) float f32x4;

static __device__ __forceinline__ float siluf(float v) {
    return v / (1.f + expf(-v));
}
static __device__ __forceinline__ unsigned short f2bf(float f) {
    unsigned int u = __float_as_uint(f);
    u = (u + 0x7FFFu + ((u >> 16) & 1u)) >> 16;   // RNE
    return (unsigned short)u;
}

// ---------------- K0: build x_seq (4,2304,192) ----------------
__global__ __launch_bounds__(256) void k_build_xseq(const float* __restrict__ x,
                                                    float* __restrict__ xseq) {
    int idx = blockIdx.x * 256 + threadIdx.x;
    if (idx >= KK * LL * DIMC) return;
    int d = idx % DIMC;
    int l = (idx / DIMC) % LL;
    int k = idx / (DIMC * LL);
    int dim = l / 12;
    int pos = (l % 12) * DIMC + d;   // in [0,2304)
    int src;
    if (k == 0)      src = pos;
    else if (k == 1) src = (pos % 48) * 48 + pos / 48;
    else if (k == 2) src = 2303 - pos;
    else { int p2 = 2303 - pos; src = (p2 % 48) * 48 + p2 / 48; }
    xseq[idx] = x[dim * LL + src];
}

// ---------------- prep: small fp32 weight slab bc|dt (384 x 40) ----------------
__global__ __launch_bounds__(256) void k_prep_small(const float* __restrict__ w_bc,
                                                    const float* __restrict__ b_bc,
                                                    const float* __restrict__ w_dt,
                                                    const float* __restrict__ dt_bias,
                                                    float* __restrict__ wsm,
                                                    float* __restrict__ bsm) {
    int idx = blockIdx.x * 256 + threadIdx.x;
    if (idx < 384 * 40) {
        int k = idx / 40, j = idx % 40;
        float v = 0.f;
        if (j < 32)      v = w_bc[k * 32 + j];
        else if (j < 38) v = w_dt[k * 6 + (j - 32)];
        wsm[idx] = v;
    }
    if (idx < 40) {
        float v = 0.f;
        if (idx < 32)      v = b_bc[idx];
        else if (idx < 38) v = dt_bias[idx - 32];
        bsm[idx] = v;
    }
}

// ---- transpose + cast fp32 in(R x C) -> bf16 out(C x R): out[c][r]=in[r][c] ----
__global__ __launch_bounds__(256) void k_tcast(const float* __restrict__ in,
                                               unsigned short* __restrict__ out,
                                               int R, int C) {
    int idx = blockIdx.x * 256 + threadIdx.x;
    if (idx >= R * C) return;
    int r = idx % R;
    int c = idx / R;
    out[idx] = f2bf(in[(size_t)r * C + c]);
}

// ---------------- silu + cast proj[:, :384] -> bf16 (9216 x 384) ----------------
__global__ __launch_bounds__(256) void k_actcast(const float* __restrict__ proj,
                                                 unsigned short* __restrict__ xb) {
    int idx = blockIdx.x * 256 + threadIdx.x;
    if (idx >= 9216 * EE) return;
    int row = idx / EE, e = idx % EE;
    xb[idx] = f2bf(siluf(proj[(size_t)row * 768 + e]));
}

// ---------------- bf16 MFMA GEMM: C(fp32) = A(bf16 MxK) * BT(bf16 NxK)^T ------
// 128x128 tile, 4 waves in 2x2, each 64x64 via 4x4 of 16x16x32 MFMA.
// Requires M%128==0, N%128==0, K%32==0.
// LDS pitch 56 shorts = 112 B (16B-aligned; fragment-read bank touches at the
// 8-per-wave minimum).
__global__ __launch_bounds__(256) void gemm_bf16(const unsigned short* __restrict__ A,
                                                 const unsigned short* __restrict__ BT,
                                                 float* __restrict__ C,
                                                 int K, int lda, int ldbt, int ldc) {
    __shared__ __align__(16) unsigned short As[128][56];
    __shared__ __align__(16) unsigned short Bs[128][56];
    int bm = blockIdx.y * 128, bn = blockIdx.x * 128;
    int tid = threadIdx.x;
    int lane = tid & 63, wave = tid >> 6;
    int wm = (wave >> 1) * 64, wn = (wave & 1) * 64;
    f32x4 acc[4][4];
#pragma unroll
    for (int f = 0; f < 4; f++)
#pragma unroll
        for (int g = 0; g < 4; g++) acc[f][g] = (f32x4){0.f, 0.f, 0.f, 0.f};

    int r = tid >> 1;            // 0..127 (tile row / BT row)
    int kh = (tid & 1) * 16;     // 0 or 16 (k offset)
    int fr = lane & 15;          // fragment row/col
    int kl = (lane >> 4) * 8;    // fragment k base

    for (int k0 = 0; k0 < K; k0 += 32) {
        const uint4* ap = (const uint4*)(A + (size_t)(bm + r) * lda + k0 + kh);
        const uint4* bp = (const uint4*)(BT + (size_t)(bn + r) * ldbt + k0 + kh);
        uint4 a0 = ap[0], a1 = ap[1];
        uint4 b0 = bp[0], b1 = bp[1];
        __syncthreads();                       // previous iter's frag reads done
        *(uint4*)&As[r][kh] = a0; *(uint4*)&As[r][kh + 8] = a1;
        *(uint4*)&Bs[r][kh] = b0; *(uint4*)&Bs[r][kh + 8] = b1;
        __syncthreads();
        bf16x8 af[4], bg[4];
#pragma unroll
        for (int f = 0; f < 4; f++) af[f] = *(const bf16x8*)&As[wm + f * 16 + fr][kl];
#pragma unroll
        for (int g = 0; g < 4; g++) bg[g] = *(const bf16x8*)&Bs[wn + g * 16 + fr][kl];
#pragma unroll
        for (int f = 0; f < 4; f++)
#pragma unroll
            for (int g = 0; g < 4; g++)
                acc[f][g] = __builtin_amdgcn_mfma_f32_16x16x32_bf16(af[f], bg[g], acc[f][g], 0, 0, 0);
    }
    // epilogue: C/D layout col=lane&15, row=(lane>>4)*4+i
    int cc = lane & 15, crb = (lane >> 4) * 4;
#pragma unroll
    for (int f = 0; f < 4; f++)
#pragma unroll
        for (int g = 0; g < 4; g++)
#pragma unroll
            for (int i = 0; i < 4; i++)
                C[(size_t)(bm + wm + f * 16 + crb + i) * ldc + bn + wn + g * 16 + cc] = acc[f][g][i];
}

// ---------------- tiled fp32 GEMM (kept for proj / bcdt / out) ----------------
template <int BM, int BNt, int TM, int TN>
__global__ __launch_bounds__(256) void gemm_f32t(const float* __restrict__ A,
                                                 const float* __restrict__ B,
                                                 const float* __restrict__ bias,
                                                 float* __restrict__ C,
                                                 int M, int N, int K,
                                                 int lda, int ldb, int ldc, int act) {
    constexpr int BKt = 16;
    constexpr int NTX = BNt / TN;
    constexpr int NTY = BM / TM;
    static_assert(NTX * NTY == 256, "need 256 threads");
    constexpr int QM = TM / 4;
    constexpr int QN = TN / 4;
    constexpr int PAD = 4;
    __shared__ float As[BKt][BM + PAD];
    __shared__ float Bs[BKt][BNt + PAD];

    int bm = blockIdx.y * BM, bn = blockIdx.x * BNt;
    int tid = threadIdx.x;
    int tx = tid % NTX, ty = tid / NTX;

    float acc[TM][TN];
#pragma unroll
    for (int i = 0; i < TM; i++)
#pragma unroll
        for (int j = 0; j < TN; j++) acc[i][j] = 0.f;

    for (int k0 = 0; k0 < K; k0 += BKt) {
        constexpr int FA = (BM * BKt) / (256 * 4);
#pragma unroll
        for (int p = 0; p < FA; ++p) {
            int fid = p * 256 + tid;
            int r = fid >> 2;
            int c4 = (fid & 3) * 4;
            const float* ap = A + (size_t)(bm + r) * lda + k0 + c4;
            float4 v = *(const float4*)ap;
            if (act) { v.x = siluf(v.x); v.y = siluf(v.y); v.z = siluf(v.z); v.w = siluf(v.w); }
            As[c4 + 0][r] = v.x;
            As[c4 + 1][r] = v.y;
            As[c4 + 2][r] = v.z;
            As[c4 + 3][r] = v.w;
        }
        constexpr int FB = (BKt * BNt) / (256 * 4);
#pragma unroll
        for (int p = 0; p < FB; ++p) {
            int fid = p * 256 + tid;
            int kk = fid / (BNt / 4);
            int c4 = (fid % (BNt / 4)) * 4;
            int cc = bn + c4;
            const float* bp = B + (size_t)(k0 + kk) * ldb + cc;
            float4 v;
            if (cc + 4 <= N) {
                v = *(const float4*)bp;
            } else {
                v.x = (cc + 0 < N) ? bp[0] : 0.f;
                v.y = (cc + 1 < N) ? bp[1] : 0.f;
                v.z = (cc + 2 < N) ? bp[2] : 0.f;
                v.w = (cc + 3 < N) ? bp[3] : 0.f;
            }
            *(float4*)&Bs[kk][c4] = v;
        }
        __syncthreads();
#pragma unroll
        for (int kk = 0; kk < BKt; kk++) {
            float av[QM * 4], bv[QN * 4];
#pragma unroll
            for (int qi = 0; qi < QM; qi++)
                *(float4*)&av[qi * 4] = *(const float4*)&As[kk][qi * (BM / 2) + ty * 4];
#pragma unroll
            for (int qj = 0; qj < QN; qj++)
                *(float4*)&bv[qj * 4] = *(const float4*)&Bs[kk][qj * (BNt / 2) + tx * 4];
#pragma unroll
            for (int i = 0; i < TM; i++)
#pragma unroll
                for (int j = 0; j < TN; j++)
                    acc[i][j] += av[i] * bv[j];
        }
        __syncthreads();
    }
#pragma unroll
    for (int qi = 0; qi < QM; qi++) {
#pragma unroll
        for (int i = 0; i < 4; i++) {
            int m = bm + qi * (BM / 2) + ty * 4 + i;
#pragma unroll
            for (int qj = 0; qj < QN; qj++) {
                int cc = bn + qj * (BNt / 2) + tx * 4;
                float4 v;
                v.x = acc[qi * 4 + i][qj * 4 + 0];
                v.y = acc[qi * 4 + i][qj * 4 + 1];
                v.z = acc[qi * 4 + i][qj * 4 + 2];
                v.w = acc[qi * 4 + i][qj * 4 + 3];
                if (bias) {
                    v.x += (cc + 0 < N) ? bias[cc + 0] : 0.f;
                    v.y += (cc + 1 < N) ? bias[cc + 1] : 0.f;
                    v.z += (cc + 2 < N) ? bias[cc + 2] : 0.f;
                    v.w += (cc + 3 < N) ? bias[cc + 3] : 0.f;
                }
                float* cp = C + (size_t)m * ldc + cc;
                if (cc + 4 <= N) {
                    *(float4*)cp = v;
                } else {
                    if (cc + 0 < N) cp[0] = v.x;
                    if (cc + 1 < N) cp[1] = v.y;
                    if (cc + 2 < N) cp[2] = v.z;
                    if (cc + 3 < N) cp[3] = v.w;
                }
            }
        }
    }
}

// ---------------- softplus/r + cumsum of dt over l, per (bh) ----------------
__global__ __launch_bounds__(256) void k_dtcum(const float* __restrict__ zxb,
                                               const float* __restrict__ A_log,
                                               float* __restrict__ dtv,
                                               float* __restrict__ rrv,
                                               float* __restrict__ cum) {
    int bh = blockIdx.x;
    int tid = threadIdx.x;
    int b = bh / HHH, h = bh % HHH;
    float aexp = expf(A_log[h]);
    const int PER = 9;                    // 256*9 = 2304
    int base = tid * PER;
    float p[PER];
    float s = 0.f;
#pragma unroll
    for (int j = 0; j < PER; j++) {
        int l = base + j;
        float xv = zxb[((size_t)b * LL + l) * ZLD + 800 + h];
        float sp = fmaxf(xv, 0.f) + log1pf(expf(-fabsf(xv)));   // softplus
        dtv[(size_t)bh * LL + l] = sp;
        rrv[(size_t)bh * LL + l] = expf(-sp * aexp);
        s += sp; p[j] = s;
    }
    __shared__ float sh[256];
    sh[tid] = s;
    __syncthreads();
    for (int off = 1; off < 256; off <<= 1) {
        float t = (tid >= off) ? sh[tid - off] : 0.f;
        __syncthreads();
        sh[tid] += t;
        __syncthreads();
    }
    float excl = sh[tid] - s;
#pragma unroll
    for (int j = 0; j < PER; j++) cum[(size_t)bh * LL + base + j] = excl + p[j];
}

// ---------------- RMS-normalize B/C and rotate -> btct (bh, l, 32) ----------------
__global__ __launch_bounds__(256) void k_rot(const float* __restrict__ zxb,
                                             const float* __restrict__ cum,
                                             const float* __restrict__ theta,
                                             float* __restrict__ btct) {
    int idx = blockIdx.x * 256 + threadIdx.x;
    if (idx >= BK_SEQ * LL) return;
    int b = idx / LL, l = idx % LL;
    const float* bcrow = zxb + ((size_t)b * LL + l) * ZLD + 768;
    float Bm[16], Cm[16];
    float sb = 0.f, sc = 0.f;
#pragma unroll
    for (int j = 0; j < 16; j++) {
        Bm[j] = bcrow[j];      sb += Bm[j] * Bm[j];
        Cm[j] = bcrow[16 + j]; sc += Cm[j] * Cm[j];
    }
    float rb = rsqrtf(sb * (1.f / 16.f) + 1e-6f);
    float rc = rsqrtf(sc * (1.f / 16.f) + 1e-6f);
#pragma unroll
    for (int h = 0; h < HHH; h++) {
        float cd = cum[((size_t)b * HHH + h) * LL + l];
        float* out = btct + (((size_t)b * HHH + h) * LL + l) * 32;
#pragma unroll
        for (int j = 0; j < 8; j++) {
            float ang = cd * theta[h * 8 + j];
            float cc = cosf(ang), ss = sinf(ang);
            float b0 = Bm[2 * j] * rb, b1 = Bm[2 * j + 1] * rb;
            out[2 * j]     = b0 * cc + b1 * ss;
            out[2 * j + 1] = -b0 * ss + b1 * cc;
            float c0 = Cm[2 * j] * rc, c1 = Cm[2 * j + 1] * rc;
            out[16 + 2 * j]     = c0 * cc + c1 * ss;
            out[16 + 2 * j + 1] = -c0 * ss + c1 * cc;
        }
    }
}

// ---------------- scan phases A (MODE 0) and C (MODE 1) ----------------
template <int MODE>
__global__ __launch_bounds__(64) void k_scan_phase(const float* __restrict__ btct,
                                                   const float* __restrict__ rrv,
                                                   const float* __restrict__ dtv,
                                                   const float* __restrict__ zxb,
                                                   const float* __restrict__ h0,
                                                   float* __restrict__ Hc,
                                                   float* __restrict__ Rc,
                                                   float* __restrict__ yD,
                                                   const float* __restrict__ Dsk) {
    int chunk = blockIdx.x;
    int bh = blockIdx.y;
    int lane = threadIdx.x;
    int b = bh / HHH, h = bh % HHH;
    int t0 = chunk * CLEN;

    __shared__ float sbt[(CLEN + 1) * 32];
    __shared__ float srd[2 * CLEN];

    const float* bt_row = btct + (size_t)bh * LL * 32;
    for (int i = lane; i < (CLEN + 1) * 8; i += 64) {
        int t = t0 - 1 + (i >> 3);
        float4 v = make_float4(0.f, 0.f, 0.f, 0.f);
        if (t >= 0)
            v = ((const float4*)(bt_row + (size_t)t * 32))[i & 7];
        ((float4*)sbt)[i] = v;
    }
    if (lane < CLEN) {
        srd[lane] = rrv[(size_t)bh * LL + t0 + lane];
        srd[CLEN + lane] = 0.5f * dtv[(size_t)bh * LL + t0 + lane];
    }

    const float* xcol = zxb + (size_t)b * LL * ZLD + EE + h * PP + lane;
    float xr[CLEN];
#pragma unroll
    for (int j = 0; j < CLEN; j++) xr[j] = xcol[(size_t)(t0 + j) * ZLD];
    float xprev = (t0 > 0) ? xcol[(size_t)(t0 - 1) * ZLD] : 0.f;

    float hreg[16];
    if (MODE == 0) {
#pragma unroll
        for (int n = 0; n < 16; n++) hreg[n] = 0.f;
    } else {
        const float* hp = h0 + ((size_t)(chunk * NBH + bh) * 16) * PP + lane;
#pragma unroll
        for (int n = 0; n < 16; n++) hreg[n] = hp[n * PP];
    }
    float dsk = (MODE == 1) ? Dsk[h] : 0.f;
    __syncthreads();

    float Btp[16];
#pragma unroll
    for (int n = 0; n < 16; n++) Btp[n] = sbt[n];
    float Rprod = 1.f;

#pragma unroll
    for (int j = 0; j < CLEN; j++) {
        float r = srd[j];
        float dhalf = srd[CLEN + j];
        float xcur = xr[j];
        const float* bb = sbt + (j + 1) * 32;
        float a = dhalf * xcur;
        float ap = dhalf * r * xprev;
        float y = 0.f;
#pragma unroll
        for (int n = 0; n < 16; n++) {
            float Btn = bb[n];
            hreg[n] = r * hreg[n] + a * Btn + ap * Btp[n];
            Btp[n] = Btn;
            if (MODE) y += bb[16 + n] * hreg[n];
        }
        xprev = xcur;
        if (MODE) {
            yD[((size_t)b * LL + t0 + j) * EE + h * PP + lane] = y + dsk * xcur;
        } else {
            Rprod *= r;
        }
    }
    if (MODE == 0) {
        float* Hp = Hc + ((size_t)(chunk * NBH + bh) * 16) * PP + lane;
#pragma unroll
        for (int n = 0; n < 16; n++) Hp[n * PP] = hreg[n];
        if (lane == 0) Rc[chunk * NBH + bh] = Rprod;
    }
}

// ---------------- scan phase B: combine chunk summaries ----------------
__global__ __launch_bounds__(64) void k_scan_combine(const float* __restrict__ Hc,
                                                     const float* __restrict__ Rc,
                                                     float* __restrict__ h0) {
    int bh = blockIdx.x;
    int lane = threadIdx.x;
    float s[16];
#pragma unroll
    for (int n = 0; n < 16; n++) s[n] = 0.f;
    float* out0 = h0 + ((size_t)(0 * NBH + bh) * 16) * PP + lane;
#pragma unroll
    for (int n = 0; n < 16; n++) out0[n * PP] = 0.f;
    for (int c = 0; c < NCHUNK - 1; ++c) {
        float R = Rc[c * NBH + bh];
        const float* Hp = Hc + ((size_t)(c * NBH + bh) * 16) * PP + lane;
        float* op = h0 + ((size_t)((c + 1) * NBH + bh) * 16) * PP + lane;
#pragma unroll
        for (int n = 0; n < 16; n++) {
            s[n] = R * s[n] + Hp[n * PP];
            op[n * PP] = s[n];
        }
    }
}

// ---------------- g = rms(y * silu(z)) * rms_w  (bf16 out) ----------------
__global__ __launch_bounds__(128) void k_gmul(const float* __restrict__ yD,
                                              const float* __restrict__ zxb,
                                              const float* __restrict__ rms_w,
                                              unsigned short* __restrict__ g) {
    int row = blockIdx.x;
    int tid = threadIdx.x;
    int lane = tid & 63, wid = tid >> 6;
    float v[3];
    float ss = 0.f;
#pragma unroll
    for (int j = 0; j < 3; j++) {
        int e = tid * 3 + j;
        float y = yD[(size_t)row * EE + e];
        float z = zxb[(size_t)row * ZLD + e];
        v[j] = y * siluf(z);
        ss += v[j] * v[j];
    }
#pragma unroll
    for (int off = 1; off < 64; off <<= 1) ss += __shfl_xor(ss, off);
    __shared__ float red[2];
    if (lane == 0) red[wid] = ss;
    __syncthreads();
    float total = red[0] + red[1];
    float scale = rsqrtf(total * (1.f / (float)EE) + 1e-6f);
#pragma unroll
    for (int j = 0; j < 3; j++) {
        int e = tid * 3 + j;
        g[(size_t)row * EE + e] = f2bf(v[j] * scale * rms_w[e]);
    }
}

// ---------------- gate + 4-direction merge -> mergedT (l, e) ----------------
__global__ __launch_bounds__(256) void k_merge(const float* __restrict__ mres,
                                               const float* __restrict__ proj,
                                               float* __restrict__ mrg) {
    int idx = blockIdx.x * 256 + threadIdx.x;
    if (idx >= LL * EE) return;
    int e = idx % EE, l = idx / EE;
    int l1 = (l % 48) * 48 + l / 48;
    int rows[4];
    rows[0] = 0 * LL + l;
    rows[1] = 1 * LL + l1;
    rows[2] = 2 * LL + (2303 - l);
    rows[3] = 3 * LL + (2303 - l1);
    float acc = 0.f;
#pragma unroll
    for (int k = 0; k < 4; k++) {
        float m = mres[(size_t)rows[k] * EE + e];
        float gz = proj[(size_t)rows[k] * 768 + EE + e];
        acc += m * siluf(gz);
    }
    mrg[idx] = acc;
}

// ---------------- LayerNorm over channels + residual ----------------
__global__ __launch_bounds__(64) void k_ln(const float* __restrict__ outT,
                                           const float* __restrict__ x,
                                           const float* __restrict__ ln_g,
                                           const float* __restrict__ ln_b,
                                           const float* __restrict__ res_scale,
                                           float* __restrict__ outF) {
    int l = blockIdx.x;
    int lane = threadIdx.x;
    float v[3];
    float s = 0.f;
#pragma unroll
    for (int j = 0; j < 3; j++) {
        int d = lane * 3 + j;
        v[j] = outT[(size_t)l * DIMC + d];
        s += v[j];
    }
#pragma unroll
    for (int off = 1; off < 64; off <<= 1) s += __shfl_xor(s, off);
    float mu = s * (1.f / (float)DIMC);
    float sq = 0.f;
#pragma unroll
    for (int j = 0; j < 3; j++) { float dlt = v[j] - mu; sq += dlt * dlt; }
#pragma unroll
    for (int off = 1; off < 64; off <<= 1) sq += __shfl_xor(sq, off);
    float rstd = rsqrtf(sq * (1.f / (float)DIMC) + 1e-5f);
    float rs = res_scale[0];
#pragma unroll
    for (int j = 0; j < 3; j++) {
        int d = lane * 3 + j;
        outF[(size_t)d * LL + l] =
            x[(size_t)d * LL + l] + rs * ((v[j] - mu) * rstd * ln_g[d] + ln_b[d]);
    }
}

// ---------------- host launcher ----------------
extern "C" void kernel_launch(void* const* d_in, const int* in_sizes, int n_in,
                              void* d_out, int out_size, void* d_ws, size_t ws_size,
                              hipStream_t stream) {
    const float* x        = (const float*)d_in[0];
    const float* w_in     = (const float*)d_in[1];
    const float* w_zx     = (const float*)d_in[2];
    const float* w_bc     = (const float*)d_in[3];
    const float* b_bc     = (const float*)d_in[4];
    const float* w_dt     = (const float*)d_in[5];
    const float* dt_bias  = (const float*)d_in[6];
    const float* A_log    = (const float*)d_in[7];
    const float* theta    = (const float*)d_in[8];
    const float* D_skip   = (const float*)d_in[9];
    const float* rms_w    = (const float*)d_in[10];
    const float* w_mout   = (const float*)d_in[11];
    const float* w_out    = (const float*)d_in[12];
    const float* ln_g     = (const float*)d_in[13];
    const float* ln_b     = (const float*)d_in[14];
    const float* res_scale= (const float*)d_in[15];
    float* outF = (float*)d_out;
    float* ws = (float*)d_ws;

    // workspace layout (float slots), with aliasing
    size_t o = 0;
    auto alloc = [&](size_t n) { size_t r = o; o += (n + 127) & ~(size_t)127; return r; };
    size_t xseq_o  = alloc(1769472);               // reused as btct after proj GEMM
    size_t proj_o  = alloc((size_t)9216 * 768);
    size_t xbf_o   = alloc((size_t)9216 * EE / 2); // bf16 silu(x_ssm); reused as g_bf
    size_t wzxT_o  = alloc((size_t)768 * 384 / 2); // bf16
    size_t wmoT_o  = alloc((size_t)384 * 384 / 2); // bf16
    size_t wsm_o   = alloc((size_t)384 * 40);
    size_t bsm_o   = alloc(40);
    size_t zxb_o   = alloc((size_t)9216 * ZLD);    // reused as mres after k_gmul
    size_t dtv_o   = alloc((size_t)NBH * LL);
    size_t rrv_o   = alloc((size_t)NBH * LL);
    size_t cum_o   = alloc((size_t)NBH * LL);
    size_t Hc_o    = alloc((size_t)NCHUNK * NBH * 16 * PP);
    size_t Rc_o    = alloc((size_t)NCHUNK * NBH);
    size_t h0_o    = alloc((size_t)NCHUNK * NBH * 16 * PP);
    size_t yD_o    = alloc((size_t)9216 * EE);
    size_t mrg_o   = alloc((size_t)LL * EE);
    size_t outT_o  = alloc((size_t)LL * DIMC);

    float* xseq = ws + xseq_o;
    float* proj = ws + proj_o;
    unsigned short* xbf  = (unsigned short*)(ws + xbf_o);
    unsigned short* wzxT = (unsigned short*)(ws + wzxT_o);
    unsigned short* wmoT = (unsigned short*)(ws + wmoT_o);
    float* wsm  = ws + wsm_o;
    float* bsm  = ws + bsm_o;
    float* zxb  = ws + zxb_o;
    float* dtv  = ws + dtv_o;
    float* rrv  = ws + rrv_o;
    float* cum  = ws + cum_o;
    float* Hc   = ws + Hc_o;
    float* Rc   = ws + Rc_o;
    float* h0   = ws + h0_o;
    float* yD   = ws + yD_o;
    float* mrg  = ws + mrg_o;
    float* outT = ws + outT_o;
    float* btct = xseq;                 // alias (xseq dead after proj GEMM)
    float* mres = zxb;                  // alias (zxb dead after k_gmul)
    unsigned short* g_bf = xbf;         // alias (xbf dead after zx MFMA GEMM)

    // 1. build x_seq
    k_build_xseq<<<(KK * LL * DIMC + 255) / 256, 256, 0, stream>>>(x, xseq);
    // 2. prep small fp32 slab + bf16 transposed weights
    k_prep_small<<<(384 * 40 + 255) / 256, 256, 0, stream>>>(w_bc, b_bc, w_dt, dt_bias, wsm, bsm);
    // w_zx is (384 x 768): out[n][k] = in[k][n] needs R=384, C=768  (round-6 bug: was swapped)
    k_tcast<<<(384 * 768 + 255) / 256, 256, 0, stream>>>(w_zx, wzxT, 384, 768);
    k_tcast<<<(384 * 384 + 255) / 256, 256, 0, stream>>>(w_mout, wmoT, 384, 384);
    // 3. proj = xseq @ w_in  (9216 x 768 x 192)  fp32
    gemm_f32t<128, 128, 8, 8><<<dim3(768 / 128, 9216 / 128), 256, 0, stream>>>(
        xseq, w_in, nullptr, proj, 9216, 768, 192, 192, 768, 768, 0);
    // 4. silu + cast to bf16
    k_actcast<<<(9216 * EE + 255) / 256, 256, 0, stream>>>(proj, xbf);
    // 5a. z|x (cols 0..767) = bf16 MFMA GEMM
    gemm_bf16<<<dim3(768 / 128, 9216 / 128), 256, 0, stream>>>(xbf, wzxT, zxb, 384, 384, 384, ZLD);
    // 5b. bc|dt (cols 768..805) fp32, numerically exact path
    gemm_f32t<64, 64, 4, 4><<<dim3(1, 9216 / 64), 256, 0, stream>>>(
        proj, wsm, bsm, zxb + 768, 9216, 38, 384, 768, 40, ZLD, 1);
    // 6. dt / r / cumsum
    k_dtcum<<<NBH, 256, 0, stream>>>(zxb, A_log, dtv, rrv, cum);
    // 7. rotate B/C
    k_rot<<<(BK_SEQ * LL + 255) / 256, 256, 0, stream>>>(zxb, cum, theta, btct);
    // 8-10. chunked scan
    k_scan_phase<0><<<dim3(NCHUNK, NBH), 64, 0, stream>>>(btct, rrv, dtv, zxb, h0, Hc, Rc, yD, D_skip);
    k_scan_combine<<<NBH, 64, 0, stream>>>(Hc, Rc, h0);
    k_scan_phase<1><<<dim3(NCHUNK, NBH), 64, 0, stream>>>(btct, rrv, dtv, zxb, h0, Hc, Rc, yD, D_skip);
    // 11. g = rms(y*silu(z))*rms_w -> bf16
    k_gmul<<<9216, 128, 0, stream>>>(yD, zxb, rms_w, g_bf);
    // 12. mres = g @ w_mout (bf16 MFMA)  [writes into zxb alias]
    gemm_bf16<<<dim3(384 / 128, 9216 / 128), 256, 0, stream>>>(g_bf, wmoT, mres, 384, 384, 384, 384);
    // 13. gate + merge 4 directions -> mergedT (l, e)
    k_merge<<<(LL * EE + 255) / 256, 256, 0, stream>>>(mres, proj, mrg);
    // 14. outT = mergedT @ w_out (2304 x 192 x 384) fp32
    gemm_f32t<64, 64, 4, 4><<<dim3(192 / 64, 2304 / 64), 256, 0, stream>>>(
        mrg, w_out, nullptr, outT, 2304, 192, 384, 384, 192, 192, 0);
    // 15. layernorm + residual -> output (192, 2304)
    k_ln<<<LL, 64, 0, stream>>>(outT, x, ln_g, ln_b, res_scale, outF);
    (void)in_sizes; (void)n_in; (void)out_size; (void)ws_size;
}

// Round 8
// 221.405 us; speedup vs baseline: 2.9547x; 1.2660x over previous
//
#include <hip/hip_runtime.h>
#include <hip/hip_bf16.h>
#include <math.h>

// ---------------- problem constants ----------------
#define BN   1
#define DIMC 192
#define HI   48
#define WI   48
#define LL   2304          // HI*WI
#define EE   384
#define NN   16
#define PP   64
#define HHH  6
#define HALF 8
#define KK   4
#define BK_SEQ (BN*KK)     // 4
#define NBH  (BK_SEQ*HHH)  // 24
#define CLEN 24
#define NCHUNK 96          // CLEN*NCHUNK == LL
#define ZLD  896           // padded leading dim for z|x|bc|dt (806 logical, 7*128)

typedef __attribute__((ext_vector_type(8))) short bf16x8;
typedef __attribute__((ext_vector_type(4))) float f32x4;

static __device__ __forceinline__ float siluf(float v) {
    return v / (1.f + expf(-v));
}
static __device__ __forceinline__ unsigned short f2bf(float f) {
    unsigned int u = __float_as_uint(f);
    u = (u + 0x7FFFu + ((u >> 16) & 1u)) >> 16;   // RNE
    return (unsigned short)u;
}

// ---------------- K0: build x_seq (4,2304,192) in bf16 ----------------
__global__ __launch_bounds__(256) void k_build_xseq(const float* __restrict__ x,
                                                    unsigned short* __restrict__ xseq) {
    int idx = blockIdx.x * 256 + threadIdx.x;
    if (idx >= KK * LL * DIMC) return;
    int d = idx % DIMC;
    int l = (idx / DIMC) % LL;
    int k = idx / (DIMC * LL);
    int dim = l / 12;
    int pos = (l % 12) * DIMC + d;   // in [0,2304)
    int src;
    if (k == 0)      src = pos;
    else if (k == 1) src = (pos % 48) * 48 + pos / 48;
    else if (k == 2) src = 2303 - pos;
    else { int p2 = 2303 - pos; src = (p2 % 48) * 48 + p2 / 48; }
    xseq[idx] = f2bf(x[dim * LL + src]);
}

// ---- transpose + cast fp32 in(R x C) -> bf16 out(C x R): out[c][r]=in[r][c] ----
__global__ __launch_bounds__(256) void k_tcast(const float* __restrict__ in,
                                               unsigned short* __restrict__ out,
                                               int R, int C) {
    int idx = blockIdx.x * 256 + threadIdx.x;
    if (idx >= R * C) return;
    int r = idx % R;
    int c = idx / R;
    out[idx] = f2bf(in[(size_t)r * C + c]);
}

// ---- prep: wcatT (896 x 384 bf16) = [w_zx | w_bc | w_dt]^T, biascat (896 fp32) ----
__global__ __launch_bounds__(256) void k_prep_wcat(const float* __restrict__ w_zx,
                                                   const float* __restrict__ w_bc,
                                                   const float* __restrict__ w_dt,
                                                   const float* __restrict__ b_bc,
                                                   const float* __restrict__ dt_bias,
                                                   unsigned short* __restrict__ wcatT,
                                                   float* __restrict__ biascat) {
    int idx = blockIdx.x * 256 + threadIdx.x;
    if (idx < ZLD * EE) {
        int n = idx / EE, k = idx % EE;
        float v = 0.f;
        if (n < 768)      v = w_zx[(size_t)k * 768 + n];
        else if (n < 800) v = w_bc[(size_t)k * 32 + (n - 768)];
        else if (n < 806) v = w_dt[(size_t)k * 6 + (n - 800)];
        wcatT[idx] = f2bf(v);
    }
    if (idx < ZLD) {
        float v = 0.f;
        if (idx >= 768 && idx < 800) v = b_bc[idx - 768];
        else if (idx >= 800 && idx < 806) v = dt_bias[idx - 800];
        biascat[idx] = v;
    }
}

// ---------------- bf16 MFMA GEMM: C(fp32) = act(A) * BT^T (+bias) ----------------
// 128x128 tile, 4 waves 2x2, each 64x64 via 4x4 of 16x16x32 MFMA.
// ACT=0: A is bf16 (lda in shorts). ACT=1: A is fp32 (lda in floats), silu+cast
// fused into the LDS staging. Requires M%128==0, N%128==0, K%32==0.
template <int ACT>
__global__ __launch_bounds__(256) void gemm_bf16(const void* __restrict__ Av,
                                                 const unsigned short* __restrict__ BT,
                                                 const float* __restrict__ bias,
                                                 float* __restrict__ C,
                                                 int K, int lda, int ldbt, int ldc) {
    __shared__ __align__(16) unsigned short As[128][56];
    __shared__ __align__(16) unsigned short Bs[128][56];
    int bm = blockIdx.y * 128, bn = blockIdx.x * 128;
    int tid = threadIdx.x;
    int lane = tid & 63, wave = tid >> 6;
    int wm = (wave >> 1) * 64, wn = (wave & 1) * 64;
    f32x4 acc[4][4];
#pragma unroll
    for (int f = 0; f < 4; f++)
#pragma unroll
        for (int g = 0; g < 4; g++) acc[f][g] = (f32x4){0.f, 0.f, 0.f, 0.f};

    int r = tid >> 1;            // 0..127 (tile row / BT row)
    int kh = (tid & 1) * 16;     // 0 or 16 (k offset)
    int fr = lane & 15;          // fragment row/col
    int kl = (lane >> 4) * 8;    // fragment k base

    for (int k0 = 0; k0 < K; k0 += 32) {
        uint4 sa0, sa1, b0, b1;
        if (ACT) {
            const float* ap = (const float*)Av + (size_t)(bm + r) * lda + k0 + kh;
            float4 v0 = ((const float4*)ap)[0];
            float4 v1 = ((const float4*)ap)[1];
            float4 v2 = ((const float4*)ap)[2];
            float4 v3 = ((const float4*)ap)[3];
            unsigned short s[16];
            s[0]  = f2bf(siluf(v0.x)); s[1]  = f2bf(siluf(v0.y));
            s[2]  = f2bf(siluf(v0.z)); s[3]  = f2bf(siluf(v0.w));
            s[4]  = f2bf(siluf(v1.x)); s[5]  = f2bf(siluf(v1.y));
            s[6]  = f2bf(siluf(v1.z)); s[7]  = f2bf(siluf(v1.w));
            s[8]  = f2bf(siluf(v2.x)); s[9]  = f2bf(siluf(v2.y));
            s[10] = f2bf(siluf(v2.z)); s[11] = f2bf(siluf(v2.w));
            s[12] = f2bf(siluf(v3.x)); s[13] = f2bf(siluf(v3.y));
            s[14] = f2bf(siluf(v3.z)); s[15] = f2bf(siluf(v3.w));
            sa0 = *(const uint4*)&s[0];
            sa1 = *(const uint4*)&s[8];
        } else {
            const uint4* ap = (const uint4*)((const unsigned short*)Av +
                                             (size_t)(bm + r) * lda + k0 + kh);
            sa0 = ap[0]; sa1 = ap[1];
        }
        {
            const uint4* bp = (const uint4*)(BT + (size_t)(bn + r) * ldbt + k0 + kh);
            b0 = bp[0]; b1 = bp[1];
        }
        __syncthreads();                       // previous iter's frag reads done
        *(uint4*)&As[r][kh] = sa0; *(uint4*)&As[r][kh + 8] = sa1;
        *(uint4*)&Bs[r][kh] = b0;  *(uint4*)&Bs[r][kh + 8] = b1;
        __syncthreads();
        bf16x8 af[4], bg[4];
#pragma unroll
        for (int f = 0; f < 4; f++) af[f] = *(const bf16x8*)&As[wm + f * 16 + fr][kl];
#pragma unroll
        for (int g = 0; g < 4; g++) bg[g] = *(const bf16x8*)&Bs[wn + g * 16 + fr][kl];
#pragma unroll
        for (int f = 0; f < 4; f++)
#pragma unroll
            for (int g = 0; g < 4; g++)
                acc[f][g] = __builtin_amdgcn_mfma_f32_16x16x32_bf16(af[f], bg[g], acc[f][g], 0, 0, 0);
    }
    // epilogue: C/D layout col=lane&15, row=(lane>>4)*4+i
    int cc = lane & 15, crb = (lane >> 4) * 4;
#pragma unroll
    for (int f = 0; f < 4; f++)
#pragma unroll
        for (int g = 0; g < 4; g++) {
            int col = bn + wn + g * 16 + cc;
            float bv = bias ? bias[col] : 0.f;
#pragma unroll
            for (int i = 0; i < 4; i++)
                C[(size_t)(bm + wm + f * 16 + crb + i) * ldc + col] = acc[f][g][i] + bv;
        }
}

// ---------------- tiled fp32 GEMM (kept for the final out GEMM) ----------------
template <int BM, int BNt, int TM, int TN>
__global__ __launch_bounds__(256) void gemm_f32t(const float* __restrict__ A,
                                                 const float* __restrict__ B,
                                                 const float* __restrict__ bias,
                                                 float* __restrict__ C,
                                                 int M, int N, int K,
                                                 int lda, int ldb, int ldc, int act) {
    constexpr int BKt = 16;
    constexpr int NTX = BNt / TN;
    constexpr int NTY = BM / TM;
    static_assert(NTX * NTY == 256, "need 256 threads");
    constexpr int QM = TM / 4;
    constexpr int QN = TN / 4;
    constexpr int PAD = 4;
    __shared__ float As[BKt][BM + PAD];
    __shared__ float Bs[BKt][BNt + PAD];

    int bm = blockIdx.y * BM, bn = blockIdx.x * BNt;
    int tid = threadIdx.x;
    int tx = tid % NTX, ty = tid / NTX;

    float acc[TM][TN];
#pragma unroll
    for (int i = 0; i < TM; i++)
#pragma unroll
        for (int j = 0; j < TN; j++) acc[i][j] = 0.f;

    for (int k0 = 0; k0 < K; k0 += BKt) {
        constexpr int FA = (BM * BKt) / (256 * 4);
#pragma unroll
        for (int p = 0; p < FA; ++p) {
            int fid = p * 256 + tid;
            int r = fid >> 2;
            int c4 = (fid & 3) * 4;
            const float* ap = A + (size_t)(bm + r) * lda + k0 + c4;
            float4 v = *(const float4*)ap;
            if (act) { v.x = siluf(v.x); v.y = siluf(v.y); v.z = siluf(v.z); v.w = siluf(v.w); }
            As[c4 + 0][r] = v.x;
            As[c4 + 1][r] = v.y;
            As[c4 + 2][r] = v.z;
            As[c4 + 3][r] = v.w;
        }
        constexpr int FB = (BKt * BNt) / (256 * 4);
#pragma unroll
        for (int p = 0; p < FB; ++p) {
            int fid = p * 256 + tid;
            int kk = fid / (BNt / 4);
            int c4 = (fid % (BNt / 4)) * 4;
            int cc = bn + c4;
            const float* bp = B + (size_t)(k0 + kk) * ldb + cc;
            float4 v;
            if (cc + 4 <= N) {
                v = *(const float4*)bp;
            } else {
                v.x = (cc + 0 < N) ? bp[0] : 0.f;
                v.y = (cc + 1 < N) ? bp[1] : 0.f;
                v.z = (cc + 2 < N) ? bp[2] : 0.f;
                v.w = (cc + 3 < N) ? bp[3] : 0.f;
            }
            *(float4*)&Bs[kk][c4] = v;
        }
        __syncthreads();
#pragma unroll
        for (int kk = 0; kk < BKt; kk++) {
            float av[QM * 4], bv[QN * 4];
#pragma unroll
            for (int qi = 0; qi < QM; qi++)
                *(float4*)&av[qi * 4] = *(const float4*)&As[kk][qi * (BM / 2) + ty * 4];
#pragma unroll
            for (int qj = 0; qj < QN; qj++)
                *(float4*)&bv[qj * 4] = *(const float4*)&Bs[kk][qj * (BNt / 2) + tx * 4];
#pragma unroll
            for (int i = 0; i < TM; i++)
#pragma unroll
                for (int j = 0; j < TN; j++)
                    acc[i][j] += av[i] * bv[j];
        }
        __syncthreads();
    }
#pragma unroll
    for (int qi = 0; qi < QM; qi++) {
#pragma unroll
        for (int i = 0; i < 4; i++) {
            int m = bm + qi * (BM / 2) + ty * 4 + i;
#pragma unroll
            for (int qj = 0; qj < QN; qj++) {
                int cc = bn + qj * (BNt / 2) + tx * 4;
                float4 v;
                v.x = acc[qi * 4 + i][qj * 4 + 0];
                v.y = acc[qi * 4 + i][qj * 4 + 1];
                v.z = acc[qi * 4 + i][qj * 4 + 2];
                v.w = acc[qi * 4 + i][qj * 4 + 3];
                if (bias) {
                    v.x += (cc + 0 < N) ? bias[cc + 0] : 0.f;
                    v.y += (cc + 1 < N) ? bias[cc + 1] : 0.f;
                    v.z += (cc + 2 < N) ? bias[cc + 2] : 0.f;
                    v.w += (cc + 3 < N) ? bias[cc + 3] : 0.f;
                }
                float* cp = C + (size_t)m * ldc + cc;
                if (cc + 4 <= N) {
                    *(float4*)cp = v;
                } else {
                    if (cc + 0 < N) cp[0] = v.x;
                    if (cc + 1 < N) cp[1] = v.y;
                    if (cc + 2 < N) cp[2] = v.z;
                    if (cc + 3 < N) cp[3] = v.w;
                }
            }
        }
    }
}

// ---------------- softplus/r + cumsum of dt over l, per (bh) ----------------
__global__ __launch_bounds__(256) void k_dtcum(const float* __restrict__ zxb,
                                               const float* __restrict__ A_log,
                                               float* __restrict__ dtv,
                                               float* __restrict__ rrv,
                                               float* __restrict__ cum) {
    int bh = blockIdx.x;
    int tid = threadIdx.x;
    int b = bh / HHH, h = bh % HHH;
    float aexp = expf(A_log[h]);
    const int PER = 9;                    // 256*9 = 2304
    int base = tid * PER;
    float p[PER];
    float s = 0.f;
#pragma unroll
    for (int j = 0; j < PER; j++) {
        int l = base + j;
        float xv = zxb[((size_t)b * LL + l) * ZLD + 800 + h];
        float sp = fmaxf(xv, 0.f) + log1pf(expf(-fabsf(xv)));   // softplus
        dtv[(size_t)bh * LL + l] = sp;
        rrv[(size_t)bh * LL + l] = expf(-sp * aexp);
        s += sp; p[j] = s;
    }
    __shared__ float sh[256];
    sh[tid] = s;
    __syncthreads();
    for (int off = 1; off < 256; off <<= 1) {
        float t = (tid >= off) ? sh[tid - off] : 0.f;
        __syncthreads();
        sh[tid] += t;
        __syncthreads();
    }
    float excl = sh[tid] - s;
#pragma unroll
    for (int j = 0; j < PER; j++) cum[(size_t)bh * LL + base + j] = excl + p[j];
}

// ---------------- RMS-normalize B/C and rotate -> btct (bh, l, 32) ----------------
__global__ __launch_bounds__(256) void k_rot(const float* __restrict__ zxb,
                                             const float* __restrict__ cum,
                                             const float* __restrict__ theta,
                                             float* __restrict__ btct) {
    int idx = blockIdx.x * 256 + threadIdx.x;
    if (idx >= BK_SEQ * LL) return;
    int b = idx / LL, l = idx % LL;
    const float* bcrow = zxb + ((size_t)b * LL + l) * ZLD + 768;
    float Bm[16], Cm[16];
    float sb = 0.f, sc = 0.f;
#pragma unroll
    for (int j = 0; j < 16; j++) {
        Bm[j] = bcrow[j];      sb += Bm[j] * Bm[j];
        Cm[j] = bcrow[16 + j]; sc += Cm[j] * Cm[j];
    }
    float rb = rsqrtf(sb * (1.f / 16.f) + 1e-6f);
    float rc = rsqrtf(sc * (1.f / 16.f) + 1e-6f);
#pragma unroll
    for (int h = 0; h < HHH; h++) {
        float cd = cum[((size_t)b * HHH + h) * LL + l];
        float* out = btct + (((size_t)b * HHH + h) * LL + l) * 32;
#pragma unroll
        for (int j = 0; j < 8; j++) {
            float ang = cd * theta[h * 8 + j];
            float cc = cosf(ang), ss = sinf(ang);
            float b0 = Bm[2 * j] * rb, b1 = Bm[2 * j + 1] * rb;
            out[2 * j]     = b0 * cc + b1 * ss;
            out[2 * j + 1] = -b0 * ss + b1 * cc;
            float c0 = Cm[2 * j] * rc, c1 = Cm[2 * j + 1] * rc;
            out[16 + 2 * j]     = c0 * cc + c1 * ss;
            out[16 + 2 * j + 1] = -c0 * ss + c1 * cc;
        }
    }
}

// ---------------- scan phases A (MODE 0) and C (MODE 1) ----------------
template <int MODE>
__global__ __launch_bounds__(64) void k_scan_phase(const float* __restrict__ btct,
                                                   const float* __restrict__ rrv,
                                                   const float* __restrict__ dtv,
                                                   const float* __restrict__ zxb,
                                                   const float* __restrict__ h0,
                                                   float* __restrict__ Hc,
                                                   float* __restrict__ Rc,
                                                   float* __restrict__ yD,
                                                   const float* __restrict__ Dsk) {
    int chunk = blockIdx.x;
    int bh = blockIdx.y;
    int lane = threadIdx.x;
    int b = bh / HHH, h = bh % HHH;
    int t0 = chunk * CLEN;

    __shared__ float sbt[(CLEN + 1) * 32];
    __shared__ float srd[2 * CLEN];

    const float* bt_row = btct + (size_t)bh * LL * 32;
    for (int i = lane; i < (CLEN + 1) * 8; i += 64) {
        int t = t0 - 1 + (i >> 3);
        float4 v = make_float4(0.f, 0.f, 0.f, 0.f);
        if (t >= 0)
            v = ((const float4*)(bt_row + (size_t)t * 32))[i & 7];
        ((float4*)sbt)[i] = v;
    }
    if (lane < CLEN) {
        srd[lane] = rrv[(size_t)bh * LL + t0 + lane];
        srd[CLEN + lane] = 0.5f * dtv[(size_t)bh * LL + t0 + lane];
    }

    const float* xcol = zxb + (size_t)b * LL * ZLD + EE + h * PP + lane;
    float xr[CLEN];
#pragma unroll
    for (int j = 0; j < CLEN; j++) xr[j] = xcol[(size_t)(t0 + j) * ZLD];
    float xprev = (t0 > 0) ? xcol[(size_t)(t0 - 1) * ZLD] : 0.f;

    float hreg[16];
    if (MODE == 0) {
#pragma unroll
        for (int n = 0; n < 16; n++) hreg[n] = 0.f;
    } else {
        const float* hp = h0 + ((size_t)(chunk * NBH + bh) * 16) * PP + lane;
#pragma unroll
        for (int n = 0; n < 16; n++) hreg[n] = hp[n * PP];
    }
    float dsk = (MODE == 1) ? Dsk[h] : 0.f;
    __syncthreads();

    float Btp[16];
#pragma unroll
    for (int n = 0; n < 16; n++) Btp[n] = sbt[n];
    float Rprod = 1.f;

#pragma unroll
    for (int j = 0; j < CLEN; j++) {
        float r = srd[j];
        float dhalf = srd[CLEN + j];
        float xcur = xr[j];
        const float* bb = sbt + (j + 1) * 32;
        float a = dhalf * xcur;
        float ap = dhalf * r * xprev;
        float y = 0.f;
#pragma unroll
        for (int n = 0; n < 16; n++) {
            float Btn = bb[n];
            hreg[n] = r * hreg[n] + a * Btn + ap * Btp[n];
            Btp[n] = Btn;
            if (MODE) y += bb[16 + n] * hreg[n];
        }
        xprev = xcur;
        if (MODE) {
            yD[((size_t)b * LL + t0 + j) * EE + h * PP + lane] = y + dsk * xcur;
        } else {
            Rprod *= r;
        }
    }
    if (MODE == 0) {
        float* Hp = Hc + ((size_t)(chunk * NBH + bh) * 16) * PP + lane;
#pragma unroll
        for (int n = 0; n < 16; n++) Hp[n * PP] = hreg[n];
        if (lane == 0) Rc[chunk * NBH + bh] = Rprod;
    }
}

// ---------------- scan phase B: combine chunk summaries ----------------
__global__ __launch_bounds__(64) void k_scan_combine(const float* __restrict__ Hc,
                                                     const float* __restrict__ Rc,
                                                     float* __restrict__ h0) {
    int bh = blockIdx.x;
    int lane = threadIdx.x;
    float s[16];
#pragma unroll
    for (int n = 0; n < 16; n++) s[n] = 0.f;
    float* out0 = h0 + ((size_t)(0 * NBH + bh) * 16) * PP + lane;
#pragma unroll
    for (int n = 0; n < 16; n++) out0[n * PP] = 0.f;
    for (int c = 0; c < NCHUNK - 1; ++c) {
        float R = Rc[c * NBH + bh];
        const float* Hp = Hc + ((size_t)(c * NBH + bh) * 16) * PP + lane;
        float* op = h0 + ((size_t)((c + 1) * NBH + bh) * 16) * PP + lane;
#pragma unroll
        for (int n = 0; n < 16; n++) {
            s[n] = R * s[n] + Hp[n * PP];
            op[n * PP] = s[n];
        }
    }
}

// ---------------- g = rms(y * silu(z)) * rms_w  (bf16 out) ----------------
__global__ __launch_bounds__(128) void k_gmul(const float* __restrict__ yD,
                                              const float* __restrict__ zxb,
                                              const float* __restrict__ rms_w,
                                              unsigned short* __restrict__ g) {
    int row = blockIdx.x;
    int tid = threadIdx.x;
    int lane = tid & 63, wid = tid >> 6;
    float v[3];
    float ss = 0.f;
#pragma unroll
    for (int j = 0; j < 3; j++) {
        int e = tid * 3 + j;
        float y = yD[(size_t)row * EE + e];
        float z = zxb[(size_t)row * ZLD + e];
        v[j] = y * siluf(z);
        ss += v[j] * v[j];
    }
#pragma unroll
    for (int off = 1; off < 64; off <<= 1) ss += __shfl_xor(ss, off);
    __shared__ float red[2];
    if (lane == 0) red[wid] = ss;
    __syncthreads();
    float total = red[0] + red[1];
    float scale = rsqrtf(total * (1.f / (float)EE) + 1e-6f);
#pragma unroll
    for (int j = 0; j < 3; j++) {
        int e = tid * 3 + j;
        g[(size_t)row * EE + e] = f2bf(v[j] * scale * rms_w[e]);
    }
}

// ---------------- gate + 4-direction merge -> mergedT (l, e) ----------------
__global__ __launch_bounds__(256) void k_merge(const float* __restrict__ mres,
                                               const float* __restrict__ proj,
                                               float* __restrict__ mrg) {
    int idx = blockIdx.x * 256 + threadIdx.x;
    if (idx >= LL * EE) return;
    int e = idx % EE, l = idx / EE;
    int l1 = (l % 48) * 48 + l / 48;
    int rows[4];
    rows[0] = 0 * LL + l;
    rows[1] = 1 * LL + l1;
    rows[2] = 2 * LL + (2303 - l);
    rows[3] = 3 * LL + (2303 - l1);
    float acc = 0.f;
#pragma unroll
    for (int k = 0; k < 4; k++) {
        float m = mres[(size_t)rows[k] * EE + e];
        float gz = proj[(size_t)rows[k] * 768 + EE + e];
        acc += m * siluf(gz);
    }
    mrg[idx] = acc;
}

// ---------------- LayerNorm over channels + residual ----------------
__global__ __launch_bounds__(64) void k_ln(const float* __restrict__ outT,
                                           const float* __restrict__ x,
                                           const float* __restrict__ ln_g,
                                           const float* __restrict__ ln_b,
                                           const float* __restrict__ res_scale,
                                           float* __restrict__ outF) {
    int l = blockIdx.x;
    int lane = threadIdx.x;
    float v[3];
    float s = 0.f;
#pragma unroll
    for (int j = 0; j < 3; j++) {
        int d = lane * 3 + j;
        v[j] = outT[(size_t)l * DIMC + d];
        s += v[j];
    }
#pragma unroll
    for (int off = 1; off < 64; off <<= 1) s += __shfl_xor(s, off);
    float mu = s * (1.f / (float)DIMC);
    float sq = 0.f;
#pragma unroll
    for (int j = 0; j < 3; j++) { float dlt = v[j] - mu; sq += dlt * dlt; }
#pragma unroll
    for (int off = 1; off < 64; off <<= 1) sq += __shfl_xor(sq, off);
    float rstd = rsqrtf(sq * (1.f / (float)DIMC) + 1e-5f);
    float rs = res_scale[0];
#pragma unroll
    for (int j = 0; j < 3; j++) {
        int d = lane * 3 + j;
        outF[(size_t)d * LL + l] =
            x[(size_t)d * LL + l] + rs * ((v[j] - mu) * rstd * ln_g[d] + ln_b[d]);
    }
}

// ---------------- host launcher ----------------
extern "C" void kernel_launch(void* const* d_in, const int* in_sizes, int n_in,
                              void* d_out, int out_size, void* d_ws, size_t ws_size,
                              hipStream_t stream) {
    const float* x        = (const float*)d_in[0];
    const float* w_in     = (const float*)d_in[1];
    const float* w_zx     = (const float*)d_in[2];
    const float* w_bc     = (const float*)d_in[3];
    const float* b_bc     = (const float*)d_in[4];
    const float* w_dt     = (const float*)d_in[5];
    const float* dt_bias  = (const float*)d_in[6];
    const float* A_log    = (const float*)d_in[7];
    const float* theta    = (const float*)d_in[8];
    const float* D_skip   = (const float*)d_in[9];
    const float* rms_w    = (const float*)d_in[10];
    const float* w_mout   = (const float*)d_in[11];
    const float* w_out    = (const float*)d_in[12];
    const float* ln_g     = (const float*)d_in[13];
    const float* ln_b     = (const float*)d_in[14];
    const float* res_scale= (const float*)d_in[15];
    float* outF = (float*)d_out;
    float* ws = (float*)d_ws;

    // workspace layout (float slots), with aliasing
    size_t o = 0;
    auto alloc = [&](size_t n) { size_t r = o; o += (n + 127) & ~(size_t)127; return r; };
    size_t xseqb_o = alloc((size_t)9216 * DIMC / 2);   // bf16
    size_t winT_o  = alloc((size_t)768 * DIMC / 2);    // bf16
    size_t wcatT_o = alloc((size_t)ZLD * EE / 2);      // bf16
    size_t wmoT_o  = alloc((size_t)384 * 384 / 2);     // bf16
    size_t bcat_o  = alloc(ZLD);
    size_t proj_o  = alloc((size_t)9216 * 768);
    size_t zxb_o   = alloc((size_t)9216 * ZLD);        // reused as mres after k_gmul
    size_t btct_o  = alloc((size_t)NBH * LL * 32);
    size_t dtv_o   = alloc((size_t)NBH * LL);
    size_t rrv_o   = alloc((size_t)NBH * LL);
    size_t cum_o   = alloc((size_t)NBH * LL);
    size_t Hc_o    = alloc((size_t)NCHUNK * NBH * 16 * PP);  // reused as g_bf after combine
    size_t Rc_o    = alloc((size_t)NCHUNK * NBH);
    size_t h0_o    = alloc((size_t)NCHUNK * NBH * 16 * PP);
    size_t yD_o    = alloc((size_t)9216 * EE);
    size_t mrg_o   = alloc((size_t)LL * EE);
    size_t outT_o  = alloc((size_t)LL * DIMC);

    unsigned short* xseqb = (unsigned short*)(ws + xseqb_o);
    unsigned short* winT  = (unsigned short*)(ws + winT_o);
    unsigned short* wcatT = (unsigned short*)(ws + wcatT_o);
    unsigned short* wmoT  = (unsigned short*)(ws + wmoT_o);
    float* bcat = ws + bcat_o;
    float* proj = ws + proj_o;
    float* zxb  = ws + zxb_o;
    float* btct = ws + btct_o;
    float* dtv  = ws + dtv_o;
    float* rrv  = ws + rrv_o;
    float* cum  = ws + cum_o;
    float* Hc   = ws + Hc_o;
    float* Rc   = ws + Rc_o;
    float* h0   = ws + h0_o;
    float* yD   = ws + yD_o;
    float* mrg  = ws + mrg_o;
    float* outT = ws + outT_o;
    float* mres = zxb;                       // alias (zxb dead after k_gmul)
    unsigned short* g_bf = (unsigned short*)Hc;  // alias (Hc dead after combine)

    // 1. build x_seq (bf16)
    k_build_xseq<<<(KK * LL * DIMC + 255) / 256, 256, 0, stream>>>(x, xseqb);
    // 2. weight preps: w_in^T (768x192), wcat^T (896x384)+bias, w_mout^T (384x384)
    k_tcast<<<(DIMC * 768 + 255) / 256, 256, 0, stream>>>(w_in, winT, DIMC, 768);
    k_prep_wcat<<<(ZLD * EE + 255) / 256, 256, 0, stream>>>(w_zx, w_bc, w_dt, b_bc, dt_bias, wcatT, bcat);
    k_tcast<<<(384 * 384 + 255) / 256, 256, 0, stream>>>(w_mout, wmoT, 384, 384);
    // 3. proj = xseq @ w_in (9216 x 768 x 192), bf16 MFMA, fp32 out
    gemm_bf16<0><<<dim3(768 / 128, 9216 / 128), 256, 0, stream>>>(
        xseqb, winT, nullptr, proj, DIMC, DIMC, DIMC, 768);
    // 4. z|x|bc|dt = silu(proj[:, :384]) @ wcat + bias (9216 x 896 x 384), silu fused
    gemm_bf16<1><<<dim3(ZLD / 128, 9216 / 128), 256, 0, stream>>>(
        proj, wcatT, bcat, zxb, EE, 768, EE, ZLD);
    // 5. dt / r / cumsum
    k_dtcum<<<NBH, 256, 0, stream>>>(zxb, A_log, dtv, rrv, cum);
    // 6. rotate B/C
    k_rot<<<(BK_SEQ * LL + 255) / 256, 256, 0, stream>>>(zxb, cum, theta, btct);
    // 7-9. chunked scan
    k_scan_phase<0><<<dim3(NCHUNK, NBH), 64, 0, stream>>>(btct, rrv, dtv, zxb, h0, Hc, Rc, yD, D_skip);
    k_scan_combine<<<NBH, 64, 0, stream>>>(Hc, Rc, h0);
    k_scan_phase<1><<<dim3(NCHUNK, NBH), 64, 0, stream>>>(btct, rrv, dtv, zxb, h0, Hc, Rc, yD, D_skip);
    // 10. g = rms(y*silu(z))*rms_w -> bf16 (into Hc alias)
    k_gmul<<<9216, 128, 0, stream>>>(yD, zxb, rms_w, g_bf);
    // 11. mres = g @ w_mout (bf16 MFMA) [into zxb alias]
    gemm_bf16<0><<<dim3(384 / 128, 9216 / 128), 256, 0, stream>>>(
        g_bf, wmoT, nullptr, mres, 384, 384, 384, 384);
    // 12. gate + merge 4 directions -> mergedT (l, e)
    k_merge<<<(LL * EE + 255) / 256, 256, 0, stream>>>(mres, proj, mrg);
    // 13. outT = mergedT @ w_out (2304 x 192 x 384) fp32
    gemm_f32t<64, 64, 4, 4><<<dim3(192 / 64, 2304 / 64), 256, 0, stream>>>(
        mrg, w_out, nullptr, outT, 2304, 192, 384, 384, 192, 192, 0);
    // 14. layernorm + residual -> output (192, 2304)
    k_ln<<<LL, 64, 0, stream>>>(outT, x, ln_g, ln_b, res_scale, outF);
    (void)in_sizes; (void)n_in; (void)out_size; (void)ws_size;
}

// Round 9
// 205.496 us; speedup vs baseline: 3.1834x; 1.0774x over previous
//
#include <hip/hip_runtime.h>
#include <hip/hip_bf16.h>
#include <math.h>

// ---------------- problem constants ----------------
#define BN   1
#define DIMC 192
#define HI   48
#define WI   48
#define LL   2304          // HI*WI
#define EE   384
#define NN   16
#define PP   64
#define HHH  6
#define HALF 8
#define KK   4
#define BK_SEQ (BN*KK)     // 4
#define NBH  (BK_SEQ*HHH)  // 24
#define CLEN 24
#define NCHUNK 96          // CLEN*NCHUNK == LL
#define ZLD  896           // padded leading dim for z|x|bc|dt (806 logical, 7*128)

typedef __attribute__((ext_vector_type(8))) short bf16x8;
typedef __attribute__((ext_vector_type(4))) float f32x4;

static __device__ __forceinline__ float siluf(float v) {
    return v / (1.f + expf(-v));
}
static __device__ __forceinline__ unsigned short f2bf(float f) {
    unsigned int u = __float_as_uint(f);
    u = (u + 0x7FFFu + ((u >> 16) & 1u)) >> 16;   // RNE
    return (unsigned short)u;
}

// ---------------- K0: build x_seq (4,2304,192) in bf16 ----------------
__global__ __launch_bounds__(256) void k_build_xseq(const float* __restrict__ x,
                                                    unsigned short* __restrict__ xseq) {
    int idx = blockIdx.x * 256 + threadIdx.x;
    if (idx >= KK * LL * DIMC) return;
    int d = idx % DIMC;
    int l = (idx / DIMC) % LL;
    int k = idx / (DIMC * LL);
    int dim = l / 12;
    int pos = (l % 12) * DIMC + d;   // in [0,2304)
    int src;
    if (k == 0)      src = pos;
    else if (k == 1) src = (pos % 48) * 48 + pos / 48;
    else if (k == 2) src = 2303 - pos;
    else { int p2 = 2303 - pos; src = (p2 % 48) * 48 + p2 / 48; }
    xseq[idx] = f2bf(x[dim * LL + src]);
}

// ---- transpose + cast fp32 in(R x C) -> bf16 out(C x R): out[c][r]=in[r][c] ----
__global__ __launch_bounds__(256) void k_tcast(const float* __restrict__ in,
                                               unsigned short* __restrict__ out,
                                               int R, int C) {
    int idx = blockIdx.x * 256 + threadIdx.x;
    if (idx >= R * C) return;
    int r = idx % R;
    int c = idx / R;
    out[idx] = f2bf(in[(size_t)r * C + c]);
}

// ---- prep: wcatT (896 x 384 bf16) = [w_zx | w_bc | w_dt]^T, biascat (896 fp32) ----
__global__ __launch_bounds__(256) void k_prep_wcat(const float* __restrict__ w_zx,
                                                   const float* __restrict__ w_bc,
                                                   const float* __restrict__ w_dt,
                                                   const float* __restrict__ b_bc,
                                                   const float* __restrict__ dt_bias,
                                                   unsigned short* __restrict__ wcatT,
                                                   float* __restrict__ biascat) {
    int idx = blockIdx.x * 256 + threadIdx.x;
    if (idx < ZLD * EE) {
        int n = idx / EE, k = idx % EE;
        float v = 0.f;
        if (n < 768)      v = w_zx[(size_t)k * 768 + n];
        else if (n < 800) v = w_bc[(size_t)k * 32 + (n - 768)];
        else if (n < 806) v = w_dt[(size_t)k * 6 + (n - 800)];
        wcatT[idx] = f2bf(v);
    }
    if (idx < ZLD) {
        float v = 0.f;
        if (idx >= 768 && idx < 800) v = b_bc[idx - 768];
        else if (idx >= 800 && idx < 806) v = dt_bias[idx - 800];
        biascat[idx] = v;
    }
}

// ---- silu + cast proj[:, :384] -> bf16 xact (9216 x 384), 4 elems/thread ----
__global__ __launch_bounds__(256) void k_actcast(const float* __restrict__ proj,
                                                 unsigned short* __restrict__ xb) {
    int idx = blockIdx.x * 256 + threadIdx.x;
    if (idx >= 9216 * EE / 4) return;
    int row = idx / (EE / 4);
    int c4 = (idx % (EE / 4)) * 4;
    float4 v = *(const float4*)&proj[(size_t)row * 768 + c4];
    unsigned short s[4];
    s[0] = f2bf(siluf(v.x)); s[1] = f2bf(siluf(v.y));
    s[2] = f2bf(siluf(v.z)); s[3] = f2bf(siluf(v.w));
    *(uint2*)&xb[(size_t)row * EE + c4] = *(const uint2*)s;
}

// ---------------- bf16 MFMA GEMM: C(fp32) = A * BT^T (+bias) ----------------
// 128x128 tile, 4 waves 2x2, each 64x64 via 4x4 of 16x16x32 MFMA.
// Register-prefetch pipeline: tile k+1 global loads issue before the MFMA
// cluster of tile k (vmcnt wait lands at next iteration's LDS store).
// Requires M%128==0, N%128==0, K%32==0.
__global__ __launch_bounds__(256) void gemm_bf16(const unsigned short* __restrict__ A,
                                                 const unsigned short* __restrict__ BT,
                                                 const float* __restrict__ bias,
                                                 float* __restrict__ C,
                                                 int K, int lda, int ldbt, int ldc) {
    __shared__ __align__(16) unsigned short As[128][56];
    __shared__ __align__(16) unsigned short Bs[128][56];
    int bm = blockIdx.y * 128, bn = blockIdx.x * 128;
    int tid = threadIdx.x;
    int lane = tid & 63, wave = tid >> 6;
    int wm = (wave >> 1) * 64, wn = (wave & 1) * 64;
    f32x4 acc[4][4];
#pragma unroll
    for (int f = 0; f < 4; f++)
#pragma unroll
        for (int g = 0; g < 4; g++) acc[f][g] = (f32x4){0.f, 0.f, 0.f, 0.f};

    int r = tid >> 1;            // 0..127 (tile row / BT row)
    int kh = (tid & 1) * 16;     // 0 or 16 (k offset)
    int fr = lane & 15;          // fragment row/col
    int kl = (lane >> 4) * 8;    // fragment k base

    const unsigned short* arow = A + (size_t)(bm + r) * lda + kh;
    const unsigned short* brow = BT + (size_t)(bn + r) * ldbt + kh;
    uint4 a0 = *(const uint4*)arow;
    uint4 a1 = *(const uint4*)(arow + 8);
    uint4 b0 = *(const uint4*)brow;
    uint4 b1 = *(const uint4*)(brow + 8);

    for (int k0 = 0; k0 < K; k0 += 32) {
        __syncthreads();                       // previous iter's frag reads done
        *(uint4*)&As[r][kh] = a0; *(uint4*)&As[r][kh + 8] = a1;
        *(uint4*)&Bs[r][kh] = b0; *(uint4*)&Bs[r][kh + 8] = b1;
        __syncthreads();
        if (k0 + 32 < K) {                     // prefetch next tile (overlaps MFMA)
            a0 = *(const uint4*)(arow + k0 + 32);
            a1 = *(const uint4*)(arow + k0 + 40);
            b0 = *(const uint4*)(brow + k0 + 32);
            b1 = *(const uint4*)(brow + k0 + 40);
        }
        bf16x8 af[4], bg[4];
#pragma unroll
        for (int f = 0; f < 4; f++) af[f] = *(const bf16x8*)&As[wm + f * 16 + fr][kl];
#pragma unroll
        for (int g = 0; g < 4; g++) bg[g] = *(const bf16x8*)&Bs[wn + g * 16 + fr][kl];
#pragma unroll
        for (int f = 0; f < 4; f++)
#pragma unroll
            for (int g = 0; g < 4; g++)
                acc[f][g] = __builtin_amdgcn_mfma_f32_16x16x32_bf16(af[f], bg[g], acc[f][g], 0, 0, 0);
    }
    // epilogue: C/D layout col=lane&15, row=(lane>>4)*4+i
    int cc = lane & 15, crb = (lane >> 4) * 4;
#pragma unroll
    for (int f = 0; f < 4; f++)
#pragma unroll
        for (int g = 0; g < 4; g++) {
            int col = bn + wn + g * 16 + cc;
            float bv = bias ? bias[col] : 0.f;
#pragma unroll
            for (int i = 0; i < 4; i++)
                C[(size_t)(bm + wm + f * 16 + crb + i) * ldc + col] = acc[f][g][i] + bv;
        }
}

// ---------------- tiled fp32 GEMM (kept for the final out GEMM) ----------------
template <int BM, int BNt, int TM, int TN>
__global__ __launch_bounds__(256) void gemm_f32t(const float* __restrict__ A,
                                                 const float* __restrict__ B,
                                                 const float* __restrict__ bias,
                                                 float* __restrict__ C,
                                                 int M, int N, int K,
                                                 int lda, int ldb, int ldc, int act) {
    constexpr int BKt = 16;
    constexpr int NTX = BNt / TN;
    constexpr int NTY = BM / TM;
    static_assert(NTX * NTY == 256, "need 256 threads");
    constexpr int QM = TM / 4;
    constexpr int QN = TN / 4;
    constexpr int PAD = 4;
    __shared__ float As[BKt][BM + PAD];
    __shared__ float Bs[BKt][BNt + PAD];

    int bm = blockIdx.y * BM, bn = blockIdx.x * BNt;
    int tid = threadIdx.x;
    int tx = tid % NTX, ty = tid / NTX;

    float acc[TM][TN];
#pragma unroll
    for (int i = 0; i < TM; i++)
#pragma unroll
        for (int j = 0; j < TN; j++) acc[i][j] = 0.f;

    for (int k0 = 0; k0 < K; k0 += BKt) {
        constexpr int FA = (BM * BKt) / (256 * 4);
#pragma unroll
        for (int p = 0; p < FA; ++p) {
            int fid = p * 256 + tid;
            int r = fid >> 2;
            int c4 = (fid & 3) * 4;
            const float* ap = A + (size_t)(bm + r) * lda + k0 + c4;
            float4 v = *(const float4*)ap;
            if (act) { v.x = siluf(v.x); v.y = siluf(v.y); v.z = siluf(v.z); v.w = siluf(v.w); }
            As[c4 + 0][r] = v.x;
            As[c4 + 1][r] = v.y;
            As[c4 + 2][r] = v.z;
            As[c4 + 3][r] = v.w;
        }
        constexpr int FB = (BKt * BNt) / (256 * 4);
#pragma unroll
        for (int p = 0; p < FB; ++p) {
            int fid = p * 256 + tid;
            int kk = fid / (BNt / 4);
            int c4 = (fid % (BNt / 4)) * 4;
            int cc = bn + c4;
            const float* bp = B + (size_t)(k0 + kk) * ldb + cc;
            float4 v;
            if (cc + 4 <= N) {
                v = *(const float4*)bp;
            } else {
                v.x = (cc + 0 < N) ? bp[0] : 0.f;
                v.y = (cc + 1 < N) ? bp[1] : 0.f;
                v.z = (cc + 2 < N) ? bp[2] : 0.f;
                v.w = (cc + 3 < N) ? bp[3] : 0.f;
            }
            *(float4*)&Bs[kk][c4] = v;
        }
        __syncthreads();
#pragma unroll
        for (int kk = 0; kk < BKt; kk++) {
            float av[QM * 4], bv[QN * 4];
#pragma unroll
            for (int qi = 0; qi < QM; qi++)
                *(float4*)&av[qi * 4] = *(const float4*)&As[kk][qi * (BM / 2) + ty * 4];
#pragma unroll
            for (int qj = 0; qj < QN; qj++)
                *(float4*)&bv[qj * 4] = *(const float4*)&Bs[kk][qj * (BNt / 2) + tx * 4];
#pragma unroll
            for (int i = 0; i < TM; i++)
#pragma unroll
                for (int j = 0; j < TN; j++)
                    acc[i][j] += av[i] * bv[j];
        }
        __syncthreads();
    }
#pragma unroll
    for (int qi = 0; qi < QM; qi++) {
#pragma unroll
        for (int i = 0; i < 4; i++) {
            int m = bm + qi * (BM / 2) + ty * 4 + i;
#pragma unroll
            for (int qj = 0; qj < QN; qj++) {
                int cc = bn + qj * (BNt / 2) + tx * 4;
                float4 v;
                v.x = acc[qi * 4 + i][qj * 4 + 0];
                v.y = acc[qi * 4 + i][qj * 4 + 1];
                v.z = acc[qi * 4 + i][qj * 4 + 2];
                v.w = acc[qi * 4 + i][qj * 4 + 3];
                if (bias) {
                    v.x += (cc + 0 < N) ? bias[cc + 0] : 0.f;
                    v.y += (cc + 1 < N) ? bias[cc + 1] : 0.f;
                    v.z += (cc + 2 < N) ? bias[cc + 2] : 0.f;
                    v.w += (cc + 3 < N) ? bias[cc + 3] : 0.f;
                }
                float* cp = C + (size_t)m * ldc + cc;
                if (cc + 4 <= N) {
                    *(float4*)cp = v;
                } else {
                    if (cc + 0 < N) cp[0] = v.x;
                    if (cc + 1 < N) cp[1] = v.y;
                    if (cc + 2 < N) cp[2] = v.z;
                    if (cc + 3 < N) cp[3] = v.w;
                }
            }
        }
    }
}

// ---------------- softplus/r + cumsum of dt over l, per (bh) ----------------
__global__ __launch_bounds__(256) void k_dtcum(const float* __restrict__ zxb,
                                               const float* __restrict__ A_log,
                                               float* __restrict__ dtv,
                                               float* __restrict__ rrv,
                                               float* __restrict__ cum) {
    int bh = blockIdx.x;
    int tid = threadIdx.x;
    int b = bh / HHH, h = bh % HHH;
    float aexp = expf(A_log[h]);
    const int PER = 9;                    // 256*9 = 2304
    int base = tid * PER;
    float p[PER];
    float s = 0.f;
#pragma unroll
    for (int j = 0; j < PER; j++) {
        int l = base + j;
        float xv = zxb[((size_t)b * LL + l) * ZLD + 800 + h];
        float sp = fmaxf(xv, 0.f) + log1pf(expf(-fabsf(xv)));   // softplus
        dtv[(size_t)bh * LL + l] = sp;
        rrv[(size_t)bh * LL + l] = expf(-sp * aexp);
        s += sp; p[j] = s;
    }
    __shared__ float sh[256];
    sh[tid] = s;
    __syncthreads();
    for (int off = 1; off < 256; off <<= 1) {
        float t = (tid >= off) ? sh[tid - off] : 0.f;
        __syncthreads();
        sh[tid] += t;
        __syncthreads();
    }
    float excl = sh[tid] - s;
#pragma unroll
    for (int j = 0; j < PER; j++) cum[(size_t)bh * LL + base + j] = excl + p[j];
}

// ---------------- RMS-normalize B/C and rotate -> btct (bh, l, 32) ----------------
__global__ __launch_bounds__(256) void k_rot(const float* __restrict__ zxb,
                                             const float* __restrict__ cum,
                                             const float* __restrict__ theta,
                                             float* __restrict__ btct) {
    int idx = blockIdx.x * 256 + threadIdx.x;
    if (idx >= BK_SEQ * LL) return;
    int b = idx / LL, l = idx % LL;
    const float* bcrow = zxb + ((size_t)b * LL + l) * ZLD + 768;
    float Bm[16], Cm[16];
    float sb = 0.f, sc = 0.f;
#pragma unroll
    for (int j = 0; j < 16; j++) {
        Bm[j] = bcrow[j];      sb += Bm[j] * Bm[j];
        Cm[j] = bcrow[16 + j]; sc += Cm[j] * Cm[j];
    }
    float rb = rsqrtf(sb * (1.f / 16.f) + 1e-6f);
    float rc = rsqrtf(sc * (1.f / 16.f) + 1e-6f);
#pragma unroll
    for (int h = 0; h < HHH; h++) {
        float cd = cum[((size_t)b * HHH + h) * LL + l];
        float* out = btct + (((size_t)b * HHH + h) * LL + l) * 32;
#pragma unroll
        for (int j = 0; j < 8; j++) {
            float ang = cd * theta[h * 8 + j];
            float cc = cosf(ang), ss = sinf(ang);
            float b0 = Bm[2 * j] * rb, b1 = Bm[2 * j + 1] * rb;
            out[2 * j]     = b0 * cc + b1 * ss;
            out[2 * j + 1] = -b0 * ss + b1 * cc;
            float c0 = Cm[2 * j] * rc, c1 = Cm[2 * j + 1] * rc;
            out[16 + 2 * j]     = c0 * cc + c1 * ss;
            out[16 + 2 * j + 1] = -c0 * ss + c1 * cc;
        }
    }
}

// ---------------- scan phases A (MODE 0) and C (MODE 1) ----------------
template <int MODE>
__global__ __launch_bounds__(64) void k_scan_phase(const float* __restrict__ btct,
                                                   const float* __restrict__ rrv,
                                                   const float* __restrict__ dtv,
                                                   const float* __restrict__ zxb,
                                                   const float* __restrict__ h0,
                                                   float* __restrict__ Hc,
                                                   float* __restrict__ Rc,
                                                   float* __restrict__ yD,
                                                   const float* __restrict__ Dsk) {
    int chunk = blockIdx.x;
    int bh = blockIdx.y;
    int lane = threadIdx.x;
    int b = bh / HHH, h = bh % HHH;
    int t0 = chunk * CLEN;

    __shared__ float sbt[(CLEN + 1) * 32];
    __shared__ float srd[2 * CLEN];

    const float* bt_row = btct + (size_t)bh * LL * 32;
    for (int i = lane; i < (CLEN + 1) * 8; i += 64) {
        int t = t0 - 1 + (i >> 3);
        float4 v = make_float4(0.f, 0.f, 0.f, 0.f);
        if (t >= 0)
            v = ((const float4*)(bt_row + (size_t)t * 32))[i & 7];
        ((float4*)sbt)[i] = v;
    }
    if (lane < CLEN) {
        srd[lane] = rrv[(size_t)bh * LL + t0 + lane];
        srd[CLEN + lane] = 0.5f * dtv[(size_t)bh * LL + t0 + lane];
    }

    const float* xcol = zxb + (size_t)b * LL * ZLD + EE + h * PP + lane;
    float xr[CLEN];
#pragma unroll
    for (int j = 0; j < CLEN; j++) xr[j] = xcol[(size_t)(t0 + j) * ZLD];
    float xprev = (t0 > 0) ? xcol[(size_t)(t0 - 1) * ZLD] : 0.f;

    float hreg[16];
    if (MODE == 0) {
#pragma unroll
        for (int n = 0; n < 16; n++) hreg[n] = 0.f;
    } else {
        const float* hp = h0 + ((size_t)(chunk * NBH + bh) * 16) * PP + lane;
#pragma unroll
        for (int n = 0; n < 16; n++) hreg[n] = hp[n * PP];
    }
    float dsk = (MODE == 1) ? Dsk[h] : 0.f;
    __syncthreads();

    float Btp[16];
#pragma unroll
    for (int n = 0; n < 16; n++) Btp[n] = sbt[n];
    float Rprod = 1.f;

#pragma unroll
    for (int j = 0; j < CLEN; j++) {
        float r = srd[j];
        float dhalf = srd[CLEN + j];
        float xcur = xr[j];
        const float* bb = sbt + (j + 1) * 32;
        float a = dhalf * xcur;
        float ap = dhalf * r * xprev;
        float y = 0.f;
#pragma unroll
        for (int n = 0; n < 16; n++) {
            float Btn = bb[n];
            hreg[n] = r * hreg[n] + a * Btn + ap * Btp[n];
            Btp[n] = Btn;
            if (MODE) y += bb[16 + n] * hreg[n];
        }
        xprev = xcur;
        if (MODE) {
            yD[((size_t)b * LL + t0 + j) * EE + h * PP + lane] = y + dsk * xcur;
        } else {
            Rprod *= r;
        }
    }
    if (MODE == 0) {
        float* Hp = Hc + ((size_t)(chunk * NBH + bh) * 16) * PP + lane;
#pragma unroll
        for (int n = 0; n < 16; n++) Hp[n * PP] = hreg[n];
        if (lane == 0) Rc[chunk * NBH + bh] = Rprod;
    }
}

// ---------------- scan phase B: combine chunk summaries ----------------
__global__ __launch_bounds__(64) void k_scan_combine(const float* __restrict__ Hc,
                                                     const float* __restrict__ Rc,
                                                     float* __restrict__ h0) {
    int bh = blockIdx.x;
    int lane = threadIdx.x;
    float s[16];
#pragma unroll
    for (int n = 0; n < 16; n++) s[n] = 0.f;
    float* out0 = h0 + ((size_t)(0 * NBH + bh) * 16) * PP + lane;
#pragma unroll
    for (int n = 0; n < 16; n++) out0[n * PP] = 0.f;
    for (int c = 0; c < NCHUNK - 1; ++c) {
        float R = Rc[c * NBH + bh];
        const float* Hp = Hc + ((size_t)(c * NBH + bh) * 16) * PP + lane;
        float* op = h0 + ((size_t)((c + 1) * NBH + bh) * 16) * PP + lane;
#pragma unroll
        for (int n = 0; n < 16; n++) {
            s[n] = R * s[n] + Hp[n * PP];
            op[n * PP] = s[n];
        }
    }
}

// ---------------- g = rms(y * silu(z)) * rms_w  (bf16 out) ----------------
__global__ __launch_bounds__(128) void k_gmul(const float* __restrict__ yD,
                                              const float* __restrict__ zxb,
                                              const float* __restrict__ rms_w,
                                              unsigned short* __restrict__ g) {
    int row = blockIdx.x;
    int tid = threadIdx.x;
    int lane = tid & 63, wid = tid >> 6;
    float v[3];
    float ss = 0.f;
#pragma unroll
    for (int j = 0; j < 3; j++) {
        int e = tid * 3 + j;
        float y = yD[(size_t)row * EE + e];
        float z = zxb[(size_t)row * ZLD + e];
        v[j] = y * siluf(z);
        ss += v[j] * v[j];
    }
#pragma unroll
    for (int off = 1; off < 64; off <<= 1) ss += __shfl_xor(ss, off);
    __shared__ float red[2];
    if (lane == 0) red[wid] = ss;
    __syncthreads();
    float total = red[0] + red[1];
    float scale = rsqrtf(total * (1.f / (float)EE) + 1e-6f);
#pragma unroll
    for (int j = 0; j < 3; j++) {
        int e = tid * 3 + j;
        g[(size_t)row * EE + e] = f2bf(v[j] * scale * rms_w[e]);
    }
}

// ---------------- gate + 4-direction merge -> mergedT (l, e) ----------------
__global__ __launch_bounds__(256) void k_merge(const float* __restrict__ mres,
                                               const float* __restrict__ proj,
                                               float* __restrict__ mrg) {
    int idx = blockIdx.x * 256 + threadIdx.x;
    if (idx >= LL * EE) return;
    int e = idx % EE, l = idx / EE;
    int l1 = (l % 48) * 48 + l / 48;
    int rows[4];
    rows[0] = 0 * LL + l;
    rows[1] = 1 * LL + l1;
    rows[2] = 2 * LL + (2303 - l);
    rows[3] = 3 * LL + (2303 - l1);
    float acc = 0.f;
#pragma unroll
    for (int k = 0; k < 4; k++) {
        float m = mres[(size_t)rows[k] * EE + e];
        float gz = proj[(size_t)rows[k] * 768 + EE + e];
        acc += m * siluf(gz);
    }
    mrg[idx] = acc;
}

// ---------------- LayerNorm over channels + residual ----------------
__global__ __launch_bounds__(64) void k_ln(const float* __restrict__ outT,
                                           const float* __restrict__ x,
                                           const float* __restrict__ ln_g,
                                           const float* __restrict__ ln_b,
                                           const float* __restrict__ res_scale,
                                           float* __restrict__ outF) {
    int l = blockIdx.x;
    int lane = threadIdx.x;
    float v[3];
    float s = 0.f;
#pragma unroll
    for (int j = 0; j < 3; j++) {
        int d = lane * 3 + j;
        v[j] = outT[(size_t)l * DIMC + d];
        s += v[j];
    }
#pragma unroll
    for (int off = 1; off < 64; off <<= 1) s += __shfl_xor(s, off);
    float mu = s * (1.f / (float)DIMC);
    float sq = 0.f;
#pragma unroll
    for (int j = 0; j < 3; j++) { float dlt = v[j] - mu; sq += dlt * dlt; }
#pragma unroll
    for (int off = 1; off < 64; off <<= 1) sq += __shfl_xor(sq, off);
    float rstd = rsqrtf(sq * (1.f / (float)DIMC) + 1e-5f);
    float rs = res_scale[0];
#pragma unroll
    for (int j = 0; j < 3; j++) {
        int d = lane * 3 + j;
        outF[(size_t)d * LL + l] =
            x[(size_t)d * LL + l] + rs * ((v[j] - mu) * rstd * ln_g[d] + ln_b[d]);
    }
}

// ---------------- host launcher ----------------
extern "C" void kernel_launch(void* const* d_in, const int* in_sizes, int n_in,
                              void* d_out, int out_size, void* d_ws, size_t ws_size,
                              hipStream_t stream) {
    const float* x        = (const float*)d_in[0];
    const float* w_in     = (const float*)d_in[1];
    const float* w_zx     = (const float*)d_in[2];
    const float* w_bc     = (const float*)d_in[3];
    const float* b_bc     = (const float*)d_in[4];
    const float* w_dt     = (const float*)d_in[5];
    const float* dt_bias  = (const float*)d_in[6];
    const float* A_log    = (const float*)d_in[7];
    const float* theta    = (const float*)d_in[8];
    const float* D_skip   = (const float*)d_in[9];
    const float* rms_w    = (const float*)d_in[10];
    const float* w_mout   = (const float*)d_in[11];
    const float* w_out    = (const float*)d_in[12];
    const float* ln_g     = (const float*)d_in[13];
    const float* ln_b     = (const float*)d_in[14];
    const float* res_scale= (const float*)d_in[15];
    float* outF = (float*)d_out;
    float* ws = (float*)d_ws;

    // workspace layout (float slots), with aliasing
    size_t o = 0;
    auto alloc = [&](size_t n) { size_t r = o; o += (n + 127) & ~(size_t)127; return r; };
    size_t xseqb_o = alloc((size_t)9216 * DIMC / 2);   // bf16
    size_t winT_o  = alloc((size_t)768 * DIMC / 2);    // bf16
    size_t wcatT_o = alloc((size_t)ZLD * EE / 2);      // bf16
    size_t wmoT_o  = alloc((size_t)384 * 384 / 2);     // bf16
    size_t bcat_o  = alloc(ZLD);
    size_t proj_o  = alloc((size_t)9216 * 768);
    size_t xact_o  = alloc((size_t)9216 * EE / 2);     // bf16 silu(x_ssm); reused as g_bf
    size_t zxb_o   = alloc((size_t)9216 * ZLD);        // reused as mres after k_gmul
    size_t btct_o  = alloc((size_t)NBH * LL * 32);
    size_t dtv_o   = alloc((size_t)NBH * LL);
    size_t rrv_o   = alloc((size_t)NBH * LL);
    size_t cum_o   = alloc((size_t)NBH * LL);
    size_t Hc_o    = alloc((size_t)NCHUNK * NBH * 16 * PP);
    size_t Rc_o    = alloc((size_t)NCHUNK * NBH);
    size_t h0_o    = alloc((size_t)NCHUNK * NBH * 16 * PP);
    size_t yD_o    = alloc((size_t)9216 * EE);
    size_t mrg_o   = alloc((size_t)LL * EE);
    size_t outT_o  = alloc((size_t)LL * DIMC);

    unsigned short* xseqb = (unsigned short*)(ws + xseqb_o);
    unsigned short* winT  = (unsigned short*)(ws + winT_o);
    unsigned short* wcatT = (unsigned short*)(ws + wcatT_o);
    unsigned short* wmoT  = (unsigned short*)(ws + wmoT_o);
    float* bcat = ws + bcat_o;
    float* proj = ws + proj_o;
    unsigned short* xact = (unsigned short*)(ws + xact_o);
    float* zxb  = ws + zxb_o;
    float* btct = ws + btct_o;
    float* dtv  = ws + dtv_o;
    float* rrv  = ws + rrv_o;
    float* cum  = ws + cum_o;
    float* Hc   = ws + Hc_o;
    float* Rc   = ws + Rc_o;
    float* h0   = ws + h0_o;
    float* yD   = ws + yD_o;
    float* mrg  = ws + mrg_o;
    float* outT = ws + outT_o;
    float* mres = zxb;                 // alias (zxb dead after k_gmul)
    unsigned short* g_bf = xact;       // alias (xact dead after zx GEMM)

    // 1. build x_seq (bf16)
    k_build_xseq<<<(KK * LL * DIMC + 255) / 256, 256, 0, stream>>>(x, xseqb);
    // 2. weight preps: w_in^T (768x192), wcat^T (896x384)+bias, w_mout^T (384x384)
    k_tcast<<<(DIMC * 768 + 255) / 256, 256, 0, stream>>>(w_in, winT, DIMC, 768);
    k_prep_wcat<<<(ZLD * EE + 255) / 256, 256, 0, stream>>>(w_zx, w_bc, w_dt, b_bc, dt_bias, wcatT, bcat);
    k_tcast<<<(384 * 384 + 255) / 256, 256, 0, stream>>>(w_mout, wmoT, 384, 384);
    // 3. proj = xseq @ w_in (9216 x 768 x 192), bf16 MFMA, fp32 out
    gemm_bf16<<<dim3(768 / 128, 9216 / 128), 256, 0, stream>>>(
        xseqb, winT, nullptr, proj, DIMC, DIMC, DIMC, 768);
    // 4. xact = silu(proj[:, :384]) bf16 (one pass)
    k_actcast<<<(9216 * EE / 4 + 255) / 256, 256, 0, stream>>>(proj, xact);
    // 5. z|x|bc|dt = xact @ wcat + bias (9216 x 896 x 384)
    gemm_bf16<<<dim3(ZLD / 128, 9216 / 128), 256, 0, stream>>>(
        xact, wcatT, bcat, zxb, EE, EE, EE, ZLD);
    // 6. dt / r / cumsum
    k_dtcum<<<NBH, 256, 0, stream>>>(zxb, A_log, dtv, rrv, cum);
    // 7. rotate B/C
    k_rot<<<(BK_SEQ * LL + 255) / 256, 256, 0, stream>>>(zxb, cum, theta, btct);
    // 8-10. chunked scan
    k_scan_phase<0><<<dim3(NCHUNK, NBH), 64, 0, stream>>>(btct, rrv, dtv, zxb, h0, Hc, Rc, yD, D_skip);
    k_scan_combine<<<NBH, 64, 0, stream>>>(Hc, Rc, h0);
    k_scan_phase<1><<<dim3(NCHUNK, NBH), 64, 0, stream>>>(btct, rrv, dtv, zxb, h0, Hc, Rc, yD, D_skip);
    // 11. g = rms(y*silu(z))*rms_w -> bf16 (into xact alias)
    k_gmul<<<9216, 128, 0, stream>>>(yD, zxb, rms_w, g_bf);
    // 12. mres = g @ w_mout (bf16 MFMA) [into zxb alias]
    gemm_bf16<<<dim3(384 / 128, 9216 / 128), 256, 0, stream>>>(
        g_bf, wmoT, nullptr, mres, 384, 384, 384, 384);
    // 13. gate + merge 4 directions -> mergedT (l, e)
    k_merge<<<(LL * EE + 255) / 256, 256, 0, stream>>>(mres, proj, mrg);
    // 14. outT = mergedT @ w_out (2304 x 192 x 384) fp32
    gemm_f32t<64, 64, 4, 4><<<dim3(192 / 64, 2304 / 64), 256, 0, stream>>>(
        mrg, w_out, nullptr, outT, 2304, 192, 384, 384, 192, 192, 0);
    // 15. layernorm + residual -> output (192, 2304)
    k_ln<<<LL, 64, 0, stream>>>(outT, x, ln_g, ln_b, res_scale, outF);
    (void)in_sizes; (void)n_in; (void)out_size; (void)ws_size;
}